// Round 22
// baseline (171.258 us; speedup 1.0000x reference)
//
#include <hip/hip_runtime.h>
#include <hip/hip_bf16.h>

namespace {
constexpr int D       = 128;
constexpr int K       = 1024;
constexpr int M_TOTAL = 65536;   // 16 * 4096
constexpr int BM      = 128;     // rows per score-block: 4 waves x 32 rows
constexpr int NCT     = K / 16;  // 64 code-tiles of 16 codes
constexpr float TAU   = 5.0e-5f; // > 2*(scorer err) + 2*(numpy quantization span)
// d_ws layout
constexpr size_t WS_CN   = 0;                    // float[1024]     (4 KB)
constexpr size_t WS_BH   = 4096;                 // short[131072]   (256 KB)
constexpr size_t WS_BL   = 4096 + 262144;        // short[131072]   (256 KB)
constexpr size_t WS_REQ  = 4096 + 2 * 262144;    // 528,384 B (confirmed, R11-R21)
constexpr size_t WS_CBT  = WS_REQ;               // float4[32768]   (512 KB)
constexpr size_t WS_REQ2 = WS_REQ + 524288;      // 1,052,672 B (confirmed, R19-R21)
}

typedef short bf16x8 __attribute__((ext_vector_type(8)));
typedef float f32x4  __attribute__((ext_vector_type(4)));

static __device__ __forceinline__ unsigned short bfbits(float x) {
  __hip_bfloat16 h = __float2bfloat16(x);   // RNE
  return *reinterpret_cast<unsigned short*>(&h);
}
static __device__ __forceinline__ float bfhi2f(unsigned short h) {
  return __uint_as_float(((unsigned)h) << 16);
}
static __device__ __forceinline__ void split8(float4 a, float4 b,
                                              bf16x8& ph, bf16x8& pl) {
  float v[8] = {a.x, a.y, a.z, a.w, b.x, b.y, b.z, b.w};
#pragma unroll
  for (int e = 0; e < 8; ++e) {
    unsigned short h = bfbits(v[e]);
    unsigned short l = bfbits(v[e] - bfhi2f(h));
    ph[e] = (short)h;
    pl[e] = (short)l;
  }
}
// numpy pairwise-8 row norm of 128 consecutive floats (R4-validated, bit-exact)
static __device__ __forceinline__ float np_norm128(const float* p) {
  float r8[8];
#pragma unroll
  for (int j = 0; j < 8; ++j) r8[j] = __fmul_rn(p[j], p[j]);
  for (int i = 8; i < D; i += 8) {
#pragma unroll
    for (int j = 0; j < 8; ++j)
      r8[j] = __fadd_rn(r8[j], __fmul_rn(p[i + j], p[i + j]));
  }
  return __fadd_rn(__fadd_rn(__fadd_rn(r8[0], r8[1]), __fadd_rn(r8[2], r8[3])),
                   __fadd_rn(__fadd_rn(r8[4], r8[5]), __fadd_rn(r8[6], r8[7])));
}

// ---------------- merged prep: Cn + cnt=0 | bf16 planes | transposed codebook ---------
__global__ void vq_prep_all(const float* __restrict__ cb, float* __restrict__ Cn,
                            int* __restrict__ cnt,
                            short* __restrict__ Bh, short* __restrict__ Bl,
                            float4* __restrict__ cbT4) {
  const int b = blockIdx.x, t = threadIdx.x;
  if (b < 4) {
    int k = b * 256 + t;
    if (b == 0 && t == 0) *cnt = 0;
    if (k < K) Cn[k] = np_norm128(cb + (size_t)k * D);
  } else if (b < 68) {
    int g = (b - 4) * 256 + t;                  // 0 .. 16383
    int code = (g >> 8) * 16 + (g & 15);
    int d0   = ((g >> 6) & 3) * 32 + ((g >> 4) & 3) * 8;
    const float* p = cb + (size_t)code * D + d0;
    float4 a = *reinterpret_cast<const float4*>(p);
    float4 bb = *reinterpret_cast<const float4*>(p + 4);
    bf16x8 ph, pl;
    split8(a, bb, ph, pl);
    *reinterpret_cast<bf16x8*>(Bh + (size_t)g * 8) = ph;
    *reinterpret_cast<bf16x8*>(Bl + (size_t)g * 8) = pl;
  } else {
    int g = (b - 68) * 256 + t;                 // 0 .. 32767
    int d = g >> 8, tt = g & 255;
    float4 v;
    v.x = cb[(size_t)(4 * tt + 0) * D + d];
    v.y = cb[(size_t)(4 * tt + 1) * D + d];
    v.z = cb[(size_t)(4 * tt + 2) * D + d];
    v.w = cb[(size_t)(4 * tt + 3) * D + d];
    cbT4[g] = v;
  }
}

// ---------------- kernel 1: SCORE — half-tile wave-private pipeline, 4 blocks/CU ------
// Half-tile (4 KB) buffers halve LDS -> 36 KB/block -> 4 blocks/CU = 4 waves/SIMD,
// doubling cross-wave pipe overlap (m114). Zero barriers in loop; per-wave vmcnt(4)
// + sched_barrier(0) (rule #18) orders each half. Acc persists across a tile's halves.
__global__ __launch_bounds__(256, 4) void vq_score(
    const float* __restrict__ z, const float* __restrict__ Cn,
    const short* __restrict__ BhG, const short* __restrict__ BlG,
    float* __restrict__ out_iF, int* __restrict__ cnt, int* __restrict__ list) {
  __shared__ __align__(16) short Bbuf[4][2][4][512];  // 4 waves x 2 half-bufs x 4 KB = 32 KB
  __shared__ float CnS[K];                             // 4 KB

  const int t    = threadIdx.x;
  const int wave = t >> 6;
  const int lane = t & 63;
  const int col  = lane & 15;
  const int baseRow = blockIdx.x * BM;

  for (int i = t; i < K; i += 256) CnS[i] = Cn[i];

  bf16x8 ah[2][4], al[2][4];
#pragma unroll
  for (int set = 0; set < 2; ++set) {
    const float* zL = z + (size_t)(baseRow + wave * 32 + set * 16 + col) * D + (lane >> 4) * 8;
#pragma unroll
    for (int ks = 0; ks < 4; ++ks) {
      float4 a = *reinterpret_cast<const float4*>(zL + ks * 32);
      float4 b = *reinterpret_cast<const float4*>(zL + ks * 32 + 4);
      split8(a, b, ah[set][ks], al[set][ks]);
    }
  }

  float s1[2][4], s2[2][4]; int i1[2][4];
#pragma unroll
  for (int s = 0; s < 2; ++s)
#pragma unroll
    for (int i = 0; i < 4; ++i) {
      s1[s][i] = 3.402823466e+38f; s2[s][i] = 3.402823466e+38f; i1[s][i] = 0;
    }

  // stage HALF h_ (ks = 2h_, 2h_+1; both planes) of tile ct_ into wave's buffer db_
#define STAGE_H(ct_, h_, db_)                                                       \
  { _Pragma("unroll")                                                               \
    for (int cc_ = 0; cc_ < 4; ++cc_) {                                             \
      int p_  = cc_ >> 1, ks_ = 2 * (h_) + (cc_ & 1);                               \
      const short* gsrc_ = (p_ ? BlG : BhG) +                                       \
                           (size_t)(((ct_) * 4 + ks_) * 64 + lane) * 8;             \
      __builtin_amdgcn_global_load_lds(                                             \
          (const __attribute__((address_space(1))) void*)gsrc_,                     \
          (__attribute__((address_space(3))) void*)&Bbuf[wave][db_][cc_][0], 16, 0, 0); \
    } }

  // compute HALF h_ from buffer db_: 12 MFMA accumulating into aA/aB/aC
#define COMP_H(db_, h_)                                                             \
  { __builtin_amdgcn_s_setprio(1);                                                  \
    _Pragma("unroll")                                                               \
    for (int j_ = 0; j_ < 2; ++j_) {                                                \
      int ks_ = 2 * (h_) + j_;                                                      \
      bf16x8 bh_c = *reinterpret_cast<const bf16x8*>(&Bbuf[wave][db_][j_][lane * 8]);     \
      bf16x8 bl_c = *reinterpret_cast<const bf16x8*>(&Bbuf[wave][db_][2 + j_][lane * 8]); \
      _Pragma("unroll")                                                             \
      for (int set_ = 0; set_ < 2; ++set_) {                                        \
        aA[set_] = __builtin_amdgcn_mfma_f32_16x16x32_bf16(ah[set_][ks_], bh_c, aA[set_], 0,0,0); \
        aB[set_] = __builtin_amdgcn_mfma_f32_16x16x32_bf16(ah[set_][ks_], bl_c, aB[set_], 0,0,0); \
        aC[set_] = __builtin_amdgcn_mfma_f32_16x16x32_bf16(al[set_][ks_], bh_c, aC[set_], 0,0,0); \
      }                                                                             \
    }                                                                               \
    __builtin_amdgcn_s_setprio(0); }

#define TRACK(ct_)                                                                  \
  { const int code_ = (ct_) * 16 + col;                                             \
    const float cn_ = CnS[code_];                                                   \
    _Pragma("unroll")                                                               \
    for (int set_ = 0; set_ < 2; ++set_) {                                          \
      _Pragma("unroll")                                                             \
      for (int reg_ = 0; reg_ < 4; ++reg_) {                                        \
        float S = fmaf(-2.0f, (aA[set_][reg_] + aB[set_][reg_]) + aC[set_][reg_], cn_); \
        if (S < s1[set_][reg_]) { s2[set_][reg_] = s1[set_][reg_];                  \
                                  s1[set_][reg_] = S; i1[set_][reg_] = code_; }     \
        else if (S < s2[set_][reg_]) { s2[set_][reg_] = S; }                        \
      }                                                                             \
    } }

#define ZERO_ACC                                                                    \
  { _Pragma("unroll")                                                               \
    for (int s_ = 0; s_ < 2; ++s_) {                                                \
      aA[s_] = (f32x4){0.f,0.f,0.f,0.f};                                            \
      aB[s_] = (f32x4){0.f,0.f,0.f,0.f};                                            \
      aC[s_] = (f32x4){0.f,0.f,0.f,0.f};                                            \
    } }

#define WAIT4  { asm volatile("s_waitcnt vmcnt(4)" ::: "memory"); \
                 __builtin_amdgcn_sched_barrier(0); }
#define WAIT0  { asm volatile("s_waitcnt vmcnt(0)" ::: "memory"); \
                 __builtin_amdgcn_sched_barrier(0); }

  f32x4 aA[2], aB[2], aC[2];

  __syncthreads();   // CnS visible (only block barrier in the kernel)
  STAGE_H(0, 0, 0); STAGE_H(0, 1, 1);   // 8 loads in flight
  for (int ct = 0; ct < NCT - 1; ++ct) {
    ZERO_ACC;
    WAIT4;  COMP_H(0, 0);  STAGE_H(ct + 1, 0, 0);
    WAIT4;  COMP_H(1, 1);  STAGE_H(ct + 1, 1, 1);
    TRACK(ct);
  }
  ZERO_ACC;
  WAIT4;  COMP_H(0, 0);
  WAIT0;  COMP_H(1, 1);
  TRACK(NCT - 1);
#undef WAIT4
#undef WAIT0
#undef STAGE_H
#undef COMP_H
#undef TRACK
#undef ZERO_ACC

  // cross-lane (16-col group) min1/min2 merge
#pragma unroll
  for (int m = 1; m < 16; m <<= 1) {
#pragma unroll
    for (int set = 0; set < 2; ++set)
#pragma unroll
      for (int reg = 0; reg < 4; ++reg) {
        float os1 = __shfl_xor(s1[set][reg], m, 64);
        float os2 = __shfl_xor(s2[set][reg], m, 64);
        int   oi  = __shfl_xor(i1[set][reg], m, 64);
        if (os1 < s1[set][reg]) {
          s2[set][reg] = fminf(s1[set][reg], os2);
          s1[set][reg] = os1; i1[set][reg] = oi;
        } else {
          s2[set][reg] = fminf(s2[set][reg], os1);
        }
      }
  }

  // write index + fused hard-row flagging
  if (col == 0) {
#pragma unroll
    for (int set = 0; set < 2; ++set)
#pragma unroll
      for (int reg = 0; reg < 4; ++reg) {
        int row = wave * 32 + set * 16 + (lane >> 4) * 4 + reg;
        size_t m = (size_t)baseRow + row;
        out_iF[m] = (float)i1[set][reg];
        if (s2[set][reg] - s1[set][reg] < TAU) {
          int p = atomicAdd(cnt, 1);
          if (p < M_TOTAL - 1) list[p] = (int)m;
        }
      }
  }
}

// ---------------- kernel 2: FULL RESCAN via transposed codebook (R19-validated) -------
__global__ __launch_bounds__(256, 4) void vq_rescan_cbT(
    const float* __restrict__ z, const float4* __restrict__ cbT4,
    const float* __restrict__ Cn,
    const int* __restrict__ cnt, const int* __restrict__ list,
    float* __restrict__ out_iF) {
  __shared__ __align__(16) float Zs[D];
  __shared__ float sRed[256];
  __shared__ int   iRed[256];
  const int t = threadIdx.x;
  int n = *cnt; if (n > M_TOTAL - 1) n = M_TOTAL - 1;

  for (int it = blockIdx.x; it < n; it += gridDim.x) {
    const int row = list[it];
    if (t < 32) {
      reinterpret_cast<float4*>(Zs)[t] =
          reinterpret_cast<const float4*>(z + (size_t)row * D)[t];
    }
    __syncthreads();

    float a0 = 0.f, a1 = 0.f, a2 = 0.f, a3 = 0.f;
#pragma unroll 8
    for (int d = 0; d < D; ++d) {
      float  zv = Zs[d];                 // LDS broadcast
      float4 cv = cbT4[(d << 8) + t];    // lane-contiguous, L2-hit
      a0 = fmaf(zv, cv.x, a0);
      a1 = fmaf(zv, cv.y, a1);
      a2 = fmaf(zv, cv.z, a2);
      a3 = fmaf(zv, cv.w, a3);
    }
    const float A = np_norm128(Zs);

    const int kb = t * 4;
    float bd = 3.402823466e+38f; int bi = 0;
    {  // ascending k, strict <: numpy first-occurrence
      float d0 = __fadd_rn(__fsub_rn(A, __fmul_rn(2.0f, a0)), Cn[kb + 0]);
      float d1 = __fadd_rn(__fsub_rn(A, __fmul_rn(2.0f, a1)), Cn[kb + 1]);
      float d2 = __fadd_rn(__fsub_rn(A, __fmul_rn(2.0f, a2)), Cn[kb + 2]);
      float d3 = __fadd_rn(__fsub_rn(A, __fmul_rn(2.0f, a3)), Cn[kb + 3]);
      if (d0 < bd) { bd = d0; bi = kb + 0; }
      if (d1 < bd) { bd = d1; bi = kb + 1; }
      if (d2 < bd) { bd = d2; bi = kb + 2; }
      if (d3 < bd) { bd = d3; bi = kb + 3; }
    }
    sRed[t] = bd; iRed[t] = bi;
    __syncthreads();
    for (int w = 128; w > 0; w >>= 1) {
      if (t < w) {
        float o = sRed[t + w]; int oi = iRed[t + w];
        if (o < sRed[t] || (o == sRed[t] && oi < iRed[t])) { sRed[t] = o; iRed[t] = oi; }
      }
      __syncthreads();
    }
    if (t == 0) out_iF[row] = (float)iRed[0];
    __syncthreads();   // protect Zs before next iteration
  }
}

// ---------------- kernel 3: EPILOGUE — pure-BW gather/STE/loss (validated absmax 0) ---
__global__ __launch_bounds__(256) void vq_epi(
    const float* __restrict__ z, const float* __restrict__ cb,
    const float* __restrict__ out_iF,
    float* __restrict__ out_zq, float* __restrict__ out_q,
    float* __restrict__ out_c) {
  const int t = threadIdx.x;
  const int r = t >> 2, q = t & 3;
  const size_t m = (size_t)blockIdx.x * 64 + r;   // grid 1024
  const int idx = (int)out_iF[m];
  const float4* cq = reinterpret_cast<const float4*>(cb + (size_t)idx * D);
  const float4* zr = reinterpret_cast<const float4*>(z + m * D);
  float4*       o4 = reinterpret_cast<float4*>(out_zq + m * D);
  float sum = 0.f;
#pragma unroll
  for (int e = 0; e < 8; ++e) {
    int d4 = q * 8 + e;
    float4 cv = cq[d4];
    float4 zv = zr[d4];
    float dx = cv.x - zv.x, dy = cv.y - zv.y, dz = cv.z - zv.z, dw = cv.w - zv.w;
    float4 st;
    st.x = zv.x + dx; st.y = zv.y + dy; st.z = zv.z + dz; st.w = zv.w + dw;
    o4[d4] = st;
    sum = fmaf(dx, dx, sum); sum = fmaf(dy, dy, sum);
    sum = fmaf(dz, dz, sum); sum = fmaf(dw, dw, sum);
  }
  sum += __shfl_xor(sum, 1, 64);
  sum += __shfl_xor(sum, 2, 64);
  if (q == 0) {
    float lv = sum * 0.0078125f;   // /128
    out_q[m] = lv;
    out_c[m] = lv;
  }
}

// ---------------- FALLBACK main: R4 kernel verbatim (validated, ~320 us) ---------------
__global__ __launch_bounds__(256) void vq_main_fp32(
    const float* __restrict__ z, const float* __restrict__ cb,
    const float* __restrict__ Cn,
    float* __restrict__ out_zq, float* __restrict__ out_q,
    float* __restrict__ out_c, float* __restrict__ out_i) {
  __shared__ float Zt[64 * D];
  __shared__ float Ct[64 * D];
  __shared__ float Arow[64];
  __shared__ int   idxArr[64];

  const int t  = threadIdx.x;
  const int ty = t >> 4;
  const int tx = t & 15;
  const int baseRow = blockIdx.x * 64;

  for (int s = t; s < 64 * (D / 4); s += 256) {
    int r = s >> 5, d4 = s & 31;
    float4 v = reinterpret_cast<const float4*>(z)[(size_t)(baseRow + r) * (D / 4) + d4];
    int colx = d4 ^ (r & 7);
    *reinterpret_cast<float4*>(&Zt[r * D + colx * 4]) = v;
  }
  __syncthreads();

  if (t < 64) {
    const int rs = t & 7;
    float r8[8];
#pragma unroll
    for (int j = 0; j < 8; ++j) {
      float v = Zt[t * D + (((j >> 2) ^ rs) << 2) + (j & 3)];
      r8[j] = __fmul_rn(v, v);
    }
    for (int i = 8; i < D; i += 8) {
#pragma unroll
      for (int j = 0; j < 8; ++j) {
        int d = i + j;
        float v = Zt[t * D + (((d >> 2) ^ rs) << 2) + (d & 3)];
        r8[j] = __fadd_rn(r8[j], __fmul_rn(v, v));
      }
    }
    Arow[t] = __fadd_rn(__fadd_rn(__fadd_rn(r8[0], r8[1]), __fadd_rn(r8[2], r8[3])),
                        __fadd_rn(__fadd_rn(r8[4], r8[5]), __fadd_rn(r8[6], r8[7])));
  }

  float s1[4]; int i1[4];
#pragma unroll
  for (int i = 0; i < 4; ++i) { s1[i] = 3.402823466e+38f; i1[i] = 0; }

  const int zsw = ty & 7;
  const int csw = tx & 7;

  for (int kt = 0; kt < 16; ++kt) {
    __syncthreads();
    for (int s = t; s < 64 * (D / 4); s += 256) {
      int r = s >> 5, d4 = s & 31;
      float4 v = reinterpret_cast<const float4*>(cb)[(size_t)(kt * 64 + r) * (D / 4) + d4];
      int colx = d4 ^ (r & 7);
      *reinterpret_cast<float4*>(&Ct[r * D + colx * 4]) = v;
    }
    __syncthreads();

    float acc[4][4];
#pragma unroll
    for (int i = 0; i < 4; ++i)
#pragma unroll
      for (int j = 0; j < 4; ++j) acc[i][j] = 0.f;

    for (int d4 = 0; d4 < 32; ++d4) {
      float4 za[4], cv[4];
      int zc = (d4 ^ zsw) * 4;
      int cc = (d4 ^ csw) * 4;
#pragma unroll
      for (int i = 0; i < 4; ++i)
        za[i] = *reinterpret_cast<const float4*>(&Zt[(ty + 16 * i) * D + zc]);
#pragma unroll
      for (int j = 0; j < 4; ++j)
        cv[j] = *reinterpret_cast<const float4*>(&Ct[(tx + 16 * j) * D + cc]);
#pragma unroll
      for (int i = 0; i < 4; ++i)
#pragma unroll
        for (int j = 0; j < 4; ++j) {
          acc[i][j] = fmaf(za[i].x, cv[j].x, acc[i][j]);
          acc[i][j] = fmaf(za[i].y, cv[j].y, acc[i][j]);
          acc[i][j] = fmaf(za[i].z, cv[j].z, acc[i][j]);
          acc[i][j] = fmaf(za[i].w, cv[j].w, acc[i][j]);
        }
    }

    float ch[4]; int kg[4];
#pragma unroll
    for (int j = 0; j < 4; ++j) {
      kg[j] = kt * 64 + tx + 16 * j;
      ch[j] = Cn[kg[j]];
    }
#pragma unroll
    for (int i = 0; i < 4; ++i) {
      float a = Arow[ty + 16 * i];
#pragma unroll
      for (int j = 0; j < 4; ++j) {
        float dist = __fadd_rn(__fsub_rn(a, __fmul_rn(2.0f, acc[i][j])), ch[j]);
        if (dist < s1[i]) { s1[i] = dist; i1[i] = kg[j]; }
      }
    }
  }

#pragma unroll
  for (int m = 1; m < 16; m <<= 1) {
#pragma unroll
    for (int i = 0; i < 4; ++i) {
      float os = __shfl_xor(s1[i], m, 64);
      int   oi = __shfl_xor(i1[i], m, 64);
      if (os < s1[i] || (os == s1[i] && oi < i1[i])) { s1[i] = os; i1[i] = oi; }
    }
  }

  if (tx == 0) {
#pragma unroll
    for (int i = 0; i < 4; ++i) idxArr[ty + 16 * i] = i1[i];
  }
  __syncthreads();

  {
    int r = t >> 2, q = t & 3;
    int idx = idxArr[r];
    size_t m = (size_t)baseRow + r;
    const float4* cq = reinterpret_cast<const float4*>(cb + (size_t)idx * D);
    const float4* zr = reinterpret_cast<const float4*>(z + m * D);
    float4*       o4 = reinterpret_cast<float4*>(out_zq + m * D);
    float sum = 0.f;
#pragma unroll
    for (int e = 0; e < 8; ++e) {
      int d4 = q * 8 + e;
      float4 cv = cq[d4];
      float4 zv = zr[d4];
      float dx = cv.x - zv.x, dy = cv.y - zv.y, dz = cv.z - zv.z, dw = cv.w - zv.w;
      float4 st;
      st.x = zv.x + dx; st.y = zv.y + dy; st.z = zv.z + dz; st.w = zv.w + dw;
      o4[d4] = st;
      sum = fmaf(dx, dx, sum); sum = fmaf(dy, dy, sum);
      sum = fmaf(dz, dz, sum); sum = fmaf(dw, dw, sum);
    }
    sum += __shfl_xor(sum, 1, 64);
    sum += __shfl_xor(sum, 2, 64);
    if (q == 0) {
      float lv = sum * 0.0078125f;
      out_q[m] = lv;
      out_c[m] = lv;
      out_i[m] = (float)idx;
    }
  }
}

extern "C" void kernel_launch(void* const* d_in, const int* in_sizes, int n_in,
                              void* d_out, int out_size, void* d_ws, size_t ws_size,
                              hipStream_t stream) {
  const float* z  = (const float*)d_in[0];   // [16,4096,128] fp32
  const float* cb = (const float*)d_in[1];   // [1024,128] fp32

  float* out0 = (float*)d_out;               // z_q_ste  [M,128]
  float* out1 = out0 + (size_t)M_TOTAL * D;  // quant_loss [M]
  float* out2 = out1 + M_TOTAL;              // commit_loss [M]
  float* out3 = out2 + M_TOTAL;              // indices (as float) [M]

  float* Cn = (float*)((char*)d_ws + WS_CN);
  int* cnt  = (int*)out2;                    // overwritten by epi afterwards
  int* list = (int*)out2 + 1;

  if (ws_size >= WS_REQ2) {
    short*  Bh   = (short*)((char*)d_ws + WS_BH);
    short*  Bl   = (short*)((char*)d_ws + WS_BL);
    float4* cbT4 = (float4*)((char*)d_ws + WS_CBT);
    vq_prep_all<<<196, 256, 0, stream>>>(cb, Cn, cnt, Bh, Bl, cbT4);
    vq_score<<<M_TOTAL / BM, 256, 0, stream>>>(z, Cn, Bh, Bl, out3, cnt, list);
    vq_rescan_cbT<<<1024, 256, 0, stream>>>(z, cbT4, Cn, cnt, list, out3);
    vq_epi<<<M_TOTAL / 64, 256, 0, stream>>>(z, cb, out3, out0, out1, out2);
  } else {
    vq_prep_all<<<4, 256, 0, stream>>>(cb, Cn, cnt, nullptr, nullptr, nullptr);
    vq_main_fp32<<<M_TOTAL / 64, 256, 0, stream>>>(z, cb, Cn, out0, out1, out2, out3);
  }
}

// Round 23
// 114.924 us; speedup vs baseline: 1.4902x; 1.4902x over previous
//
#include <hip/hip_runtime.h>
#include <hip/hip_bf16.h>

namespace {
constexpr int D       = 128;
constexpr int K       = 1024;
constexpr int M_TOTAL = 65536;   // 16 * 4096
constexpr int BM      = 128;     // rows per score-block: 4 waves x 32 rows
constexpr int NCT     = K / 16;  // 64 code-tiles of 16 codes
constexpr float TAU   = 5.0e-5f; // > 2*(scorer err) + 2*(numpy quantization span)
// d_ws layout
constexpr size_t WS_CN   = 0;                    // float[1024]     (4 KB)
constexpr size_t WS_BH   = 4096;                 // short[131072]   (256 KB)
constexpr size_t WS_BL   = 4096 + 262144;        // short[131072]   (256 KB)
constexpr size_t WS_REQ  = 4096 + 2 * 262144;    // 528,384 B (confirmed, R11-R22)
constexpr size_t WS_CBT  = WS_REQ;               // float4[32768]   (512 KB)
constexpr size_t WS_REQ2 = WS_REQ + 524288;      // 1,052,672 B (confirmed, R19-R22)
}

typedef short bf16x8 __attribute__((ext_vector_type(8)));
typedef float f32x4  __attribute__((ext_vector_type(4)));

static __device__ __forceinline__ unsigned short bfbits(float x) {
  __hip_bfloat16 h = __float2bfloat16(x);   // RNE
  return *reinterpret_cast<unsigned short*>(&h);
}
static __device__ __forceinline__ float bfhi2f(unsigned short h) {
  return __uint_as_float(((unsigned)h) << 16);
}
static __device__ __forceinline__ void split8(float4 a, float4 b,
                                              bf16x8& ph, bf16x8& pl) {
  float v[8] = {a.x, a.y, a.z, a.w, b.x, b.y, b.z, b.w};
#pragma unroll
  for (int e = 0; e < 8; ++e) {
    unsigned short h = bfbits(v[e]);
    unsigned short l = bfbits(v[e] - bfhi2f(h));
    ph[e] = (short)h;
    pl[e] = (short)l;
  }
}
// numpy pairwise-8 row norm of 128 consecutive floats (R4-validated, bit-exact)
static __device__ __forceinline__ float np_norm128(const float* p) {
  float r8[8];
#pragma unroll
  for (int j = 0; j < 8; ++j) r8[j] = __fmul_rn(p[j], p[j]);
  for (int i = 8; i < D; i += 8) {
#pragma unroll
    for (int j = 0; j < 8; ++j)
      r8[j] = __fadd_rn(r8[j], __fmul_rn(p[i + j], p[i + j]));
  }
  return __fadd_rn(__fadd_rn(__fadd_rn(r8[0], r8[1]), __fadd_rn(r8[2], r8[3])),
                   __fadd_rn(__fadd_rn(r8[4], r8[5]), __fadd_rn(r8[6], r8[7])));
}

// ---------------- merged prep: Cn + cnt=0 | bf16 planes | transposed codebook ---------
__global__ void vq_prep_all(const float* __restrict__ cb, float* __restrict__ Cn,
                            int* __restrict__ cnt,
                            short* __restrict__ Bh, short* __restrict__ Bl,
                            float4* __restrict__ cbT4) {
  const int b = blockIdx.x, t = threadIdx.x;
  if (b < 4) {
    int k = b * 256 + t;
    if (b == 0 && t == 0) *cnt = 0;
    if (k < K) Cn[k] = np_norm128(cb + (size_t)k * D);
  } else if (b < 68) {
    int g = (b - 4) * 256 + t;                  // 0 .. 16383
    int code = (g >> 8) * 16 + (g & 15);
    int d0   = ((g >> 6) & 3) * 32 + ((g >> 4) & 3) * 8;
    const float* p = cb + (size_t)code * D + d0;
    float4 a = *reinterpret_cast<const float4*>(p);
    float4 bb = *reinterpret_cast<const float4*>(p + 4);
    bf16x8 ph, pl;
    split8(a, bb, ph, pl);
    *reinterpret_cast<bf16x8*>(Bh + (size_t)g * 8) = ph;
    *reinterpret_cast<bf16x8*>(Bl + (size_t)g * 8) = pl;
  } else {
    int g = (b - 68) * 256 + t;                 // 0 .. 32767
    int d = g >> 8, tt = g & 255;
    float4 v;
    v.x = cb[(size_t)(4 * tt + 0) * D + d];
    v.y = cb[(size_t)(4 * tt + 1) * D + d];
    v.z = cb[(size_t)(4 * tt + 2) * D + d];
    v.w = cb[(size_t)(4 * tt + 3) * D + d];
    cbT4[g] = v;
  }
}

// ---------------- kernel 1: SCORE — R19-proven 4-deep pipeline + fused flag + epilogue -
__global__ __launch_bounds__(256, 2) void vq_score(
    const float* __restrict__ z, const float* __restrict__ cb,
    const float* __restrict__ Cn,
    const short* __restrict__ BhG, const short* __restrict__ BlG,
    float* __restrict__ out_zq, float* __restrict__ out_q,
    float* __restrict__ out_iF, int* __restrict__ cnt, int* __restrict__ list) {
  __shared__ __align__(16) short Bbuf[4][8][512];   // 32 KB
  __shared__ float CnS[K];                           // 4 KB
  __shared__ int   idxW[4][32];                      // per-wave row indices

  const int t    = threadIdx.x;
  const int wave = t >> 6;
  const int lane = t & 63;
  const int col  = lane & 15;
  const int baseRow = blockIdx.x * BM;

  for (int i = t; i < K; i += 256) CnS[i] = Cn[i];

  bf16x8 ah[2][4], al[2][4];
#pragma unroll
  for (int set = 0; set < 2; ++set) {
    const float* zL = z + (size_t)(baseRow + wave * 32 + set * 16 + col) * D + (lane >> 4) * 8;
#pragma unroll
    for (int ks = 0; ks < 4; ++ks) {
      float4 a = *reinterpret_cast<const float4*>(zL + ks * 32);
      float4 b = *reinterpret_cast<const float4*>(zL + ks * 32 + 4);
      split8(a, b, ah[set][ks], al[set][ks]);
    }
  }

  float s1[2][4], s2[2][4]; int i1[2][4];
#pragma unroll
  for (int s = 0; s < 2; ++s)
#pragma unroll
    for (int i = 0; i < 4; ++i) {
      s1[s][i] = 3.402823466e+38f; s2[s][i] = 3.402823466e+38f; i1[s][i] = 0;
    }

#define STAGE(ct_, bi_)                                                             \
  { _Pragma("unroll")                                                               \
    for (int i_ = 0; i_ < 2; ++i_) {                                                \
      int c_  = wave * 2 + i_;                                                      \
      int p_  = c_ >> 2, ks_ = c_ & 3;                                              \
      const short* gsrc_ = (p_ ? BlG : BhG) +                                       \
                           (size_t)(((ct_) * 4 + ks_) * 64 + lane) * 8;             \
      __builtin_amdgcn_global_load_lds(                                             \
          (const __attribute__((address_space(1))) void*)gsrc_,                     \
          (__attribute__((address_space(3))) void*)&Bbuf[bi_][c_][0], 16, 0, 0);    \
    } }

#define COMP(bi_, ct_)                                                              \
  { bf16x8 bh_c[4], bl_c[4];                                                        \
    _Pragma("unroll")                                                               \
    for (int ks_ = 0; ks_ < 4; ++ks_) {                                             \
      bh_c[ks_] = *reinterpret_cast<const bf16x8*>(&Bbuf[bi_][ks_][lane * 8]);      \
      bl_c[ks_] = *reinterpret_cast<const bf16x8*>(&Bbuf[bi_][4 + ks_][lane * 8]);  \
    }                                                                               \
    const int code_ = (ct_) * 16 + col;                                             \
    const float cn_ = CnS[code_];                                                   \
    __builtin_amdgcn_s_setprio(1);                                                  \
    _Pragma("unroll")                                                               \
    for (int set_ = 0; set_ < 2; ++set_) {                                          \
      f32x4 aA = (f32x4){0.f,0.f,0.f,0.f};                                          \
      f32x4 aB = (f32x4){0.f,0.f,0.f,0.f};                                          \
      f32x4 aC = (f32x4){0.f,0.f,0.f,0.f};                                          \
      _Pragma("unroll")                                                             \
      for (int ks_ = 0; ks_ < 4; ++ks_) {                                           \
        aA = __builtin_amdgcn_mfma_f32_16x16x32_bf16(ah[set_][ks_], bh_c[ks_], aA, 0,0,0); \
        aB = __builtin_amdgcn_mfma_f32_16x16x32_bf16(ah[set_][ks_], bl_c[ks_], aB, 0,0,0); \
        aC = __builtin_amdgcn_mfma_f32_16x16x32_bf16(al[set_][ks_], bh_c[ks_], aC, 0,0,0); \
      }                                                                             \
      _Pragma("unroll")                                                             \
      for (int reg_ = 0; reg_ < 4; ++reg_) {                                        \
        float S = fmaf(-2.0f, (aA[reg_] + aB[reg_]) + aC[reg_], cn_);               \
        if (S < s1[set_][reg_]) { s2[set_][reg_] = s1[set_][reg_];                  \
                                  s1[set_][reg_] = S; i1[set_][reg_] = code_; }     \
        else if (S < s2[set_][reg_]) { s2[set_][reg_] = S; }                        \
      }                                                                             \
    }                                                                               \
    __builtin_amdgcn_s_setprio(0); }

#define PHASE(t_, bi_)                                                              \
  { asm volatile("s_waitcnt vmcnt(4)" ::: "memory");                                \
    __builtin_amdgcn_s_barrier();                                                   \
    __builtin_amdgcn_sched_barrier(0);                                              \
    COMP(bi_, t_);                                                                  \
    STAGE(((t_) + 3) & 63, ((bi_) + 3) & 3); }

  __syncthreads();   // CnS visible
  STAGE(0, 0); STAGE(1, 1); STAGE(2, 2);
  for (int g = 0; g < NCT; g += 4) {
    PHASE(g + 0, 0);
    PHASE(g + 1, 1);
    PHASE(g + 2, 2);
    PHASE(g + 3, 3);
  }
#undef PHASE
#undef STAGE
#undef COMP

  // cross-lane (16-col group) min1/min2 merge
#pragma unroll
  for (int m = 1; m < 16; m <<= 1) {
#pragma unroll
    for (int set = 0; set < 2; ++set)
#pragma unroll
      for (int reg = 0; reg < 4; ++reg) {
        float os1 = __shfl_xor(s1[set][reg], m, 64);
        float os2 = __shfl_xor(s2[set][reg], m, 64);
        int   oi  = __shfl_xor(i1[set][reg], m, 64);
        if (os1 < s1[set][reg]) {
          s2[set][reg] = fminf(s1[set][reg], os2);
          s1[set][reg] = os1; i1[set][reg] = oi;
        } else {
          s2[set][reg] = fminf(s2[set][reg], os1);
        }
      }
  }

  // idx -> per-wave LDS + fused hard-row flagging (wave-local: no block barrier needed)
  if (col == 0) {
#pragma unroll
    for (int set = 0; set < 2; ++set)
#pragma unroll
      for (int reg = 0; reg < 4; ++reg) {
        int wr = set * 16 + (lane >> 4) * 4 + reg;     // 0..31 within wave
        idxW[wave][wr] = i1[set][reg];
        if (s2[set][reg] - s1[set][reg] < TAU) {
          int p = atomicAdd(cnt, 1);
          if (p < M_TOTAL - 1) list[p] = (int)(baseRow + wave * 32 + wr);
        }
      }
  }
  // same-wave LDS write->read: in-order per wave, compiler inserts lgkmcnt

  // fused epilogue: wave writes z_q/quant_loss/idx for its 32 rows (2 lanes per row)
  {
    const int r = lane >> 1, q = lane & 1;
    const size_t m = (size_t)baseRow + wave * 32 + r;
    const int idx = idxW[wave][r];
    const float4* cq = reinterpret_cast<const float4*>(cb + (size_t)idx * D) + q * 16;
    const float4* zr = reinterpret_cast<const float4*>(z + m * D) + q * 16;
    float4*       o4 = reinterpret_cast<float4*>(out_zq + m * D) + q * 16;
    float sum = 0.f;
#pragma unroll
    for (int e = 0; e < 16; ++e) {
      float4 cv = cq[e];
      float4 zv = zr[e];
      float dx = cv.x - zv.x, dy = cv.y - zv.y, dz = cv.z - zv.z, dw = cv.w - zv.w;
      float4 st;
      st.x = zv.x + dx; st.y = zv.y + dy; st.z = zv.z + dz; st.w = zv.w + dw;
      o4[e] = st;
      sum = fmaf(dx, dx, sum); sum = fmaf(dy, dy, sum);
      sum = fmaf(dz, dz, sum); sum = fmaf(dw, dw, sum);
    }
    sum += __shfl_xor(sum, 1, 64);
    if (q == 0) {
      float lv = sum * 0.0078125f;   // /128
      out_q[m]  = lv;
      out_iF[m] = (float)idx;
    }
  }
}

// ---------------- kernel 2: FULL RESCAN via cbT — also rewrites z_q/loss/idx ----------
__global__ __launch_bounds__(256, 4) void vq_rescan_cbT(
    const float* __restrict__ z, const float* __restrict__ cb,
    const float4* __restrict__ cbT4, const float* __restrict__ Cn,
    const int* __restrict__ cnt, const int* __restrict__ list,
    float* __restrict__ out_zq, float* __restrict__ out_q,
    float* __restrict__ out_iF) {
  __shared__ __align__(16) float Zs[D];
  __shared__ float sRed[256];
  __shared__ int   iRed[256];
  const int t = threadIdx.x;
  int n = *cnt; if (n > M_TOTAL - 1) n = M_TOTAL - 1;

  for (int it = blockIdx.x; it < n; it += gridDim.x) {
    const int row = list[it];
    if (t < 32) {
      reinterpret_cast<float4*>(Zs)[t] =
          reinterpret_cast<const float4*>(z + (size_t)row * D)[t];
    }
    __syncthreads();

    float a0 = 0.f, a1 = 0.f, a2 = 0.f, a3 = 0.f;
#pragma unroll 8
    for (int d = 0; d < D; ++d) {
      float  zv = Zs[d];                 // LDS broadcast
      float4 cv = cbT4[(d << 8) + t];    // lane-contiguous, L2-hit
      a0 = fmaf(zv, cv.x, a0);
      a1 = fmaf(zv, cv.y, a1);
      a2 = fmaf(zv, cv.z, a2);
      a3 = fmaf(zv, cv.w, a3);
    }
    const float A = np_norm128(Zs);

    const int kb = t * 4;
    float bd = 3.402823466e+38f; int bi = 0;
    {  // ascending k, strict <: numpy first-occurrence
      float d0 = __fadd_rn(__fsub_rn(A, __fmul_rn(2.0f, a0)), Cn[kb + 0]);
      float d1 = __fadd_rn(__fsub_rn(A, __fmul_rn(2.0f, a1)), Cn[kb + 1]);
      float d2 = __fadd_rn(__fsub_rn(A, __fmul_rn(2.0f, a2)), Cn[kb + 2]);
      float d3 = __fadd_rn(__fsub_rn(A, __fmul_rn(2.0f, a3)), Cn[kb + 3]);
      if (d0 < bd) { bd = d0; bi = kb + 0; }
      if (d1 < bd) { bd = d1; bi = kb + 1; }
      if (d2 < bd) { bd = d2; bi = kb + 2; }
      if (d3 < bd) { bd = d3; bi = kb + 3; }
    }
    sRed[t] = bd; iRed[t] = bi;
    __syncthreads();
    for (int w = 128; w > 0; w >>= 1) {
      if (t < w) {
        float o = sRed[t + w]; int oi = iRed[t + w];
        if (o < sRed[t] || (o == sRed[t] && oi < iRed[t])) { sRed[t] = o; iRed[t] = oi; }
      }
      __syncthreads();
    }
    // rewrite this row's outputs with the exact winner
    const int win = iRed[0];
    if (t < 32) {
      float4 zv = reinterpret_cast<const float4*>(Zs)[t];
      float4 cv = reinterpret_cast<const float4*>(cb + (size_t)win * D)[t];
      float dx = cv.x - zv.x, dy = cv.y - zv.y, dz = cv.z - zv.z, dw = cv.w - zv.w;
      float4 st;
      st.x = zv.x + dx; st.y = zv.y + dy; st.z = zv.z + dz; st.w = zv.w + dw;
      reinterpret_cast<float4*>(out_zq + (size_t)row * D)[t] = st;
      float sq = fmaf(dx, dx, fmaf(dy, dy, fmaf(dz, dz, dw * dw)));
      sq += __shfl_xor(sq, 1, 64);  sq += __shfl_xor(sq, 2, 64);
      sq += __shfl_xor(sq, 4, 64);  sq += __shfl_xor(sq, 8, 64);
      sq += __shfl_xor(sq, 16, 64);
      if (t == 0) {
        out_q[row]  = sq * 0.0078125f;
        out_iF[row] = (float)win;
      }
    }
    __syncthreads();   // protect Zs before next iteration
  }
}

// ---------------- kernel 3: commit_loss = quant_loss (after rescan; frees out2 scratch)
__global__ void vq_copy(const float* __restrict__ q, float* __restrict__ c) {
  int m = blockIdx.x * 256 + threadIdx.x;
  c[m] = q[m];
}

// ---------------- FALLBACK main: R4 kernel verbatim (validated, ~320 us) ---------------
__global__ __launch_bounds__(256) void vq_main_fp32(
    const float* __restrict__ z, const float* __restrict__ cb,
    const float* __restrict__ Cn,
    float* __restrict__ out_zq, float* __restrict__ out_q,
    float* __restrict__ out_c, float* __restrict__ out_i) {
  __shared__ float Zt[64 * D];
  __shared__ float Ct[64 * D];
  __shared__ float Arow[64];
  __shared__ int   idxArr[64];

  const int t  = threadIdx.x;
  const int ty = t >> 4;
  const int tx = t & 15;
  const int baseRow = blockIdx.x * 64;

  for (int s = t; s < 64 * (D / 4); s += 256) {
    int r = s >> 5, d4 = s & 31;
    float4 v = reinterpret_cast<const float4*>(z)[(size_t)(baseRow + r) * (D / 4) + d4];
    int colx = d4 ^ (r & 7);
    *reinterpret_cast<float4*>(&Zt[r * D + colx * 4]) = v;
  }
  __syncthreads();

  if (t < 64) {
    const int rs = t & 7;
    float r8[8];
#pragma unroll
    for (int j = 0; j < 8; ++j) {
      float v = Zt[t * D + (((j >> 2) ^ rs) << 2) + (j & 3)];
      r8[j] = __fmul_rn(v, v);
    }
    for (int i = 8; i < D; i += 8) {
#pragma unroll
      for (int j = 0; j < 8; ++j) {
        int d = i + j;
        float v = Zt[t * D + (((d >> 2) ^ rs) << 2) + (d & 3)];
        r8[j] = __fadd_rn(r8[j], __fmul_rn(v, v));
      }
    }
    Arow[t] = __fadd_rn(__fadd_rn(__fadd_rn(r8[0], r8[1]), __fadd_rn(r8[2], r8[3])),
                        __fadd_rn(__fadd_rn(r8[4], r8[5]), __fadd_rn(r8[6], r8[7])));
  }

  float s1[4]; int i1[4];
#pragma unroll
  for (int i = 0; i < 4; ++i) { s1[i] = 3.402823466e+38f; i1[i] = 0; }

  const int zsw = ty & 7;
  const int csw = tx & 7;

  for (int kt = 0; kt < 16; ++kt) {
    __syncthreads();
    for (int s = t; s < 64 * (D / 4); s += 256) {
      int r = s >> 5, d4 = s & 31;
      float4 v = reinterpret_cast<const float4*>(cb)[(size_t)(kt * 64 + r) * (D / 4) + d4];
      int colx = d4 ^ (r & 7);
      *reinterpret_cast<float4*>(&Ct[r * D + colx * 4]) = v;
    }
    __syncthreads();

    float acc[4][4];
#pragma unroll
    for (int i = 0; i < 4; ++i)
#pragma unroll
      for (int j = 0; j < 4; ++j) acc[i][j] = 0.f;

    for (int d4 = 0; d4 < 32; ++d4) {
      float4 za[4], cv[4];
      int zc = (d4 ^ zsw) * 4;
      int cc = (d4 ^ csw) * 4;
#pragma unroll
      for (int i = 0; i < 4; ++i)
        za[i] = *reinterpret_cast<const float4*>(&Zt[(ty + 16 * i) * D + zc]);
#pragma unroll
      for (int j = 0; j < 4; ++j)
        cv[j] = *reinterpret_cast<const float4*>(&Ct[(tx + 16 * j) * D + cc]);
#pragma unroll
      for (int i = 0; i < 4; ++i)
#pragma unroll
        for (int j = 0; j < 4; ++j) {
          acc[i][j] = fmaf(za[i].x, cv[j].x, acc[i][j]);
          acc[i][j] = fmaf(za[i].y, cv[j].y, acc[i][j]);
          acc[i][j] = fmaf(za[i].z, cv[j].z, acc[i][j]);
          acc[i][j] = fmaf(za[i].w, cv[j].w, acc[i][j]);
        }
    }

    float ch[4]; int kg[4];
#pragma unroll
    for (int j = 0; j < 4; ++j) {
      kg[j] = kt * 64 + tx + 16 * j;
      ch[j] = Cn[kg[j]];
    }
#pragma unroll
    for (int i = 0; i < 4; ++i) {
      float a = Arow[ty + 16 * i];
#pragma unroll
      for (int j = 0; j < 4; ++j) {
        float dist = __fadd_rn(__fsub_rn(a, __fmul_rn(2.0f, acc[i][j])), ch[j]);
        if (dist < s1[i]) { s1[i] = dist; i1[i] = kg[j]; }
      }
    }
  }

#pragma unroll
  for (int m = 1; m < 16; m <<= 1) {
#pragma unroll
    for (int i = 0; i < 4; ++i) {
      float os = __shfl_xor(s1[i], m, 64);
      int   oi = __shfl_xor(i1[i], m, 64);
      if (os < s1[i] || (os == s1[i] && oi < i1[i])) { s1[i] = os; i1[i] = oi; }
    }
  }

  if (tx == 0) {
#pragma unroll
    for (int i = 0; i < 4; ++i) idxArr[ty + 16 * i] = i1[i];
  }
  __syncthreads();

  {
    int r = t >> 2, q = t & 3;
    int idx = idxArr[r];
    size_t m = (size_t)baseRow + r;
    const float4* cq = reinterpret_cast<const float4*>(cb + (size_t)idx * D);
    const float4* zr = reinterpret_cast<const float4*>(z + m * D);
    float4*       o4 = reinterpret_cast<float4*>(out_zq + m * D);
    float sum = 0.f;
#pragma unroll
    for (int e = 0; e < 8; ++e) {
      int d4 = q * 8 + e;
      float4 cv = cq[d4];
      float4 zv = zr[d4];
      float dx = cv.x - zv.x, dy = cv.y - zv.y, dz = cv.z - zv.z, dw = cv.w - zv.w;
      float4 st;
      st.x = zv.x + dx; st.y = zv.y + dy; st.z = zv.z + dz; st.w = zv.w + dw;
      o4[d4] = st;
      sum = fmaf(dx, dx, sum); sum = fmaf(dy, dy, sum);
      sum = fmaf(dz, dz, sum); sum = fmaf(dw, dw, sum);
    }
    sum += __shfl_xor(sum, 1, 64);
    sum += __shfl_xor(sum, 2, 64);
    if (q == 0) {
      float lv = sum * 0.0078125f;
      out_q[m] = lv;
      out_c[m] = lv;
      out_i[m] = (float)idx;
    }
  }
}

extern "C" void kernel_launch(void* const* d_in, const int* in_sizes, int n_in,
                              void* d_out, int out_size, void* d_ws, size_t ws_size,
                              hipStream_t stream) {
  const float* z  = (const float*)d_in[0];   // [16,4096,128] fp32
  const float* cb = (const float*)d_in[1];   // [1024,128] fp32

  float* out0 = (float*)d_out;               // z_q_ste  [M,128]
  float* out1 = out0 + (size_t)M_TOTAL * D;  // quant_loss [M]
  float* out2 = out1 + M_TOTAL;              // commit_loss [M]
  float* out3 = out2 + M_TOTAL;              // indices (as float) [M]

  float* Cn = (float*)((char*)d_ws + WS_CN);
  // cnt/list live in out2 during score+rescan; vq_copy then writes commit_loss there.
  int* cnt  = (int*)out2;
  int* list = (int*)out2 + 1;

  if (ws_size >= WS_REQ2) {
    short*  Bh   = (short*)((char*)d_ws + WS_BH);
    short*  Bl   = (short*)((char*)d_ws + WS_BL);
    float4* cbT4 = (float4*)((char*)d_ws + WS_CBT);
    vq_prep_all<<<196, 256, 0, stream>>>(cb, Cn, cnt, Bh, Bl, cbT4);
    vq_score<<<M_TOTAL / BM, 256, 0, stream>>>(z, cb, Cn, Bh, Bl,
                                               out0, out1, out3, cnt, list);
    vq_rescan_cbT<<<1024, 256, 0, stream>>>(z, cb, cbT4, Cn, cnt, list,
                                            out0, out1, out3);
    vq_copy<<<M_TOTAL / 256, 256, 0, stream>>>(out1, out2);
  } else {
    vq_prep_all<<<4, 256, 0, stream>>>(cb, Cn, cnt, nullptr, nullptr, nullptr);
    vq_main_fp32<<<M_TOTAL / 64, 256, 0, stream>>>(z, cb, Cn, out0, out1, out2, out3);
  }
}

// Round 24
// 110.472 us; speedup vs baseline: 1.5502x; 1.0403x over previous
//
#include <hip/hip_runtime.h>
#include <hip/hip_bf16.h>

namespace {
constexpr int D       = 128;
constexpr int K       = 1024;
constexpr int M_TOTAL = 65536;   // 16 * 4096
constexpr int BM      = 128;     // rows per score-block: 4 waves x 32 rows
constexpr int NCT     = K / 16;  // 64 code-tiles of 16 codes
constexpr float TAU   = 5.0e-5f; // > 2*(scorer err) + 2*(numpy quantization span)
// d_ws layout
constexpr size_t WS_CN   = 0;                    // float[1024]     (4 KB)
constexpr size_t WS_BH   = 4096;                 // short[131072]   (256 KB)
constexpr size_t WS_BL   = 4096 + 262144;        // short[131072]   (256 KB)
constexpr size_t WS_REQ  = 4096 + 2 * 262144;    // 528,384 B (confirmed, R11-R23)
constexpr size_t WS_CBT  = WS_REQ;               // float4[32768]   (512 KB)
constexpr size_t WS_REQ2 = WS_REQ + 524288;      // 1,052,672 B (confirmed, R19-R23)
}

typedef short bf16x8 __attribute__((ext_vector_type(8)));
typedef float f32x4  __attribute__((ext_vector_type(4)));

static __device__ __forceinline__ unsigned short bfbits(float x) {
  __hip_bfloat16 h = __float2bfloat16(x);   // RNE
  return *reinterpret_cast<unsigned short*>(&h);
}
static __device__ __forceinline__ float bfhi2f(unsigned short h) {
  return __uint_as_float(((unsigned)h) << 16);
}
static __device__ __forceinline__ void split8(float4 a, float4 b,
                                              bf16x8& ph, bf16x8& pl) {
  float v[8] = {a.x, a.y, a.z, a.w, b.x, b.y, b.z, b.w};
#pragma unroll
  for (int e = 0; e < 8; ++e) {
    unsigned short h = bfbits(v[e]);
    unsigned short l = bfbits(v[e] - bfhi2f(h));
    ph[e] = (short)h;
    pl[e] = (short)l;
  }
}
// numpy pairwise-8 row norm of 128 consecutive floats (R4-validated, bit-exact)
static __device__ __forceinline__ float np_norm128(const float* p) {
  float r8[8];
#pragma unroll
  for (int j = 0; j < 8; ++j) r8[j] = __fmul_rn(p[j], p[j]);
  for (int i = 8; i < D; i += 8) {
#pragma unroll
    for (int j = 0; j < 8; ++j)
      r8[j] = __fadd_rn(r8[j], __fmul_rn(p[i + j], p[i + j]));
  }
  return __fadd_rn(__fadd_rn(__fadd_rn(r8[0], r8[1]), __fadd_rn(r8[2], r8[3])),
                   __fadd_rn(__fadd_rn(r8[4], r8[5]), __fadd_rn(r8[6], r8[7])));
}

// ---------------- merged prep: Cn + cnt=0 | bf16 planes | transposed codebook ---------
__global__ void vq_prep_all(const float* __restrict__ cb, float* __restrict__ Cn,
                            int* __restrict__ cnt,
                            short* __restrict__ Bh, short* __restrict__ Bl,
                            float4* __restrict__ cbT4) {
  const int b = blockIdx.x, t = threadIdx.x;
  if (b < 4) {
    int k = b * 256 + t;
    if (b == 0 && t == 0) *cnt = 0;
    if (k < K) Cn[k] = np_norm128(cb + (size_t)k * D);
  } else if (b < 68) {
    int g = (b - 4) * 256 + t;                  // 0 .. 16383
    int code = (g >> 8) * 16 + (g & 15);
    int d0   = ((g >> 6) & 3) * 32 + ((g >> 4) & 3) * 8;
    const float* p = cb + (size_t)code * D + d0;
    float4 a = *reinterpret_cast<const float4*>(p);
    float4 bb = *reinterpret_cast<const float4*>(p + 4);
    bf16x8 ph, pl;
    split8(a, bb, ph, pl);
    *reinterpret_cast<bf16x8*>(Bh + (size_t)g * 8) = ph;
    *reinterpret_cast<bf16x8*>(Bl + (size_t)g * 8) = pl;
  } else {
    int g = (b - 68) * 256 + t;                 // 0 .. 32767
    int d = g >> 8, tt = g & 255;
    float4 v;
    v.x = cb[(size_t)(4 * tt + 0) * D + d];
    v.y = cb[(size_t)(4 * tt + 1) * D + d];
    v.z = cb[(size_t)(4 * tt + 2) * D + d];
    v.w = cb[(size_t)(4 * tt + 3) * D + d];
    cbT4[g] = v;
  }
}

// ---------------- kernel 1: SCORE — 4 slots x 2 tiles/slot (32 phases) + fused epi ----
__global__ __launch_bounds__(256, 2) void vq_score(
    const float* __restrict__ z, const float* __restrict__ cb,
    const float* __restrict__ Cn,
    const short* __restrict__ BhG, const short* __restrict__ BlG,
    float* __restrict__ out_zq, float* __restrict__ out_q,
    float* __restrict__ out_iF, int* __restrict__ cnt, int* __restrict__ list) {
  __shared__ __align__(16) short Bbuf[4][2][8][512];  // 4 slots x 2 tiles x 8 KB = 64 KB
  __shared__ float CnS[K];                             // 4 KB
  __shared__ int   idxW[4][32];                        // per-wave row indices

  const int t    = threadIdx.x;
  const int wave = t >> 6;
  const int lane = t & 63;
  const int col  = lane & 15;
  const int baseRow = blockIdx.x * BM;

  for (int i = t; i < K; i += 256) CnS[i] = Cn[i];

  bf16x8 ah[2][4], al[2][4];
#pragma unroll
  for (int set = 0; set < 2; ++set) {
    const float* zL = z + (size_t)(baseRow + wave * 32 + set * 16 + col) * D + (lane >> 4) * 8;
#pragma unroll
    for (int ks = 0; ks < 4; ++ks) {
      float4 a = *reinterpret_cast<const float4*>(zL + ks * 32);
      float4 b = *reinterpret_cast<const float4*>(zL + ks * 32 + 4);
      split8(a, b, ah[set][ks], al[set][ks]);
    }
  }

  float s1[2][4], s2[2][4]; int i1[2][4];
#pragma unroll
  for (int s = 0; s < 2; ++s)
#pragma unroll
    for (int i = 0; i < 4; ++i) {
      s1[s][i] = 3.402823466e+38f; s2[s][i] = 3.402823466e+38f; i1[s][i] = 0;
    }

  // stage tiles ct_, ct_+1 into slot sl_ (4 loads/thread: 2 tiles x 2 chunks)
#define STAGE2(ct_, sl_)                                                            \
  { _Pragma("unroll")                                                               \
    for (int i_ = 0; i_ < 4; ++i_) {                                                \
      int ti_ = i_ >> 1;                                                            \
      int c_  = wave * 2 + (i_ & 1);                                                \
      int p_  = c_ >> 2, ks_ = c_ & 3;                                              \
      const short* gsrc_ = (p_ ? BlG : BhG) +                                       \
                           (size_t)((((ct_) + ti_) * 4 + ks_) * 64 + lane) * 8;     \
      __builtin_amdgcn_global_load_lds(                                             \
          (const __attribute__((address_space(1))) void*)gsrc_,                     \
          (__attribute__((address_space(3))) void*)&Bbuf[sl_][ti_][c_][0], 16, 0, 0); \
    } }

#define COMP(sl_, ti_, ct_)                                                         \
  { bf16x8 bh_c[4], bl_c[4];                                                        \
    _Pragma("unroll")                                                               \
    for (int ks_ = 0; ks_ < 4; ++ks_) {                                             \
      bh_c[ks_] = *reinterpret_cast<const bf16x8*>(&Bbuf[sl_][ti_][ks_][lane * 8]);      \
      bl_c[ks_] = *reinterpret_cast<const bf16x8*>(&Bbuf[sl_][ti_][4 + ks_][lane * 8]);  \
    }                                                                               \
    const int code_ = (ct_) * 16 + col;                                             \
    const float cn_ = CnS[code_];                                                   \
    __builtin_amdgcn_s_setprio(1);                                                  \
    _Pragma("unroll")                                                               \
    for (int set_ = 0; set_ < 2; ++set_) {                                          \
      f32x4 aA = (f32x4){0.f,0.f,0.f,0.f};                                          \
      f32x4 aB = (f32x4){0.f,0.f,0.f,0.f};                                          \
      f32x4 aC = (f32x4){0.f,0.f,0.f,0.f};                                          \
      _Pragma("unroll")                                                             \
      for (int ks_ = 0; ks_ < 4; ++ks_) {                                           \
        aA = __builtin_amdgcn_mfma_f32_16x16x32_bf16(ah[set_][ks_], bh_c[ks_], aA, 0,0,0); \
        aB = __builtin_amdgcn_mfma_f32_16x16x32_bf16(ah[set_][ks_], bl_c[ks_], aB, 0,0,0); \
        aC = __builtin_amdgcn_mfma_f32_16x16x32_bf16(al[set_][ks_], bh_c[ks_], aC, 0,0,0); \
      }                                                                             \
      _Pragma("unroll")                                                             \
      for (int reg_ = 0; reg_ < 4; ++reg_) {                                        \
        float S = fmaf(-2.0f, (aA[reg_] + aB[reg_]) + aC[reg_], cn_);               \
        if (S < s1[set_][reg_]) { s2[set_][reg_] = s1[set_][reg_];                  \
                                  s1[set_][reg_] = S; i1[set_][reg_] = code_; }     \
        else if (S < s2[set_][reg_]) { s2[set_][reg_] = S; }                        \
      }                                                                             \
    }                                                                               \
    __builtin_amdgcn_s_setprio(0); }

  // phase: vmcnt(8) = 2 newer slots stay in flight; barrier; 2 tiles; prefetch 2 tiles
#define PHASE(g_, sl_)                                                              \
  { asm volatile("s_waitcnt vmcnt(8)" ::: "memory");                                \
    __builtin_amdgcn_s_barrier();                                                   \
    __builtin_amdgcn_sched_barrier(0);                                              \
    COMP(sl_, 0, 2 * (g_));                                                         \
    COMP(sl_, 1, 2 * (g_) + 1);                                                     \
    STAGE2((2 * (g_) + 6) & 63, ((sl_) + 3) & 3); }

  __syncthreads();   // CnS visible
  STAGE2(0, 0); STAGE2(2, 1); STAGE2(4, 2);   // 12 loads/thread in flight
  for (int g = 0; g < NCT / 2; g += 4) {
    PHASE(g + 0, 0);
    PHASE(g + 1, 1);
    PHASE(g + 2, 2);
    PHASE(g + 3, 3);
  }
#undef PHASE
#undef STAGE2
#undef COMP

  // cross-lane (16-col group) min1/min2 merge
#pragma unroll
  for (int m = 1; m < 16; m <<= 1) {
#pragma unroll
    for (int set = 0; set < 2; ++set)
#pragma unroll
      for (int reg = 0; reg < 4; ++reg) {
        float os1 = __shfl_xor(s1[set][reg], m, 64);
        float os2 = __shfl_xor(s2[set][reg], m, 64);
        int   oi  = __shfl_xor(i1[set][reg], m, 64);
        if (os1 < s1[set][reg]) {
          s2[set][reg] = fminf(s1[set][reg], os2);
          s1[set][reg] = os1; i1[set][reg] = oi;
        } else {
          s2[set][reg] = fminf(s2[set][reg], os1);
        }
      }
  }

  // idx -> per-wave LDS + fused hard-row flagging (wave-local)
  if (col == 0) {
#pragma unroll
    for (int set = 0; set < 2; ++set)
#pragma unroll
      for (int reg = 0; reg < 4; ++reg) {
        int wr = set * 16 + (lane >> 4) * 4 + reg;     // 0..31 within wave
        idxW[wave][wr] = i1[set][reg];
        if (s2[set][reg] - s1[set][reg] < TAU) {
          int p = atomicAdd(cnt, 1);
          if (p < M_TOTAL - 1) list[p] = (int)(baseRow + wave * 32 + wr);
        }
      }
  }
  // same-wave LDS write->read: in-order per wave

  // fused epilogue: wave writes z_q/quant_loss/idx for its 32 rows (2 lanes per row)
  {
    const int r = lane >> 1, q = lane & 1;
    const size_t m = (size_t)baseRow + wave * 32 + r;
    const int idx = idxW[wave][r];
    const float4* cq = reinterpret_cast<const float4*>(cb + (size_t)idx * D) + q * 16;
    const float4* zr = reinterpret_cast<const float4*>(z + m * D) + q * 16;
    float4*       o4 = reinterpret_cast<float4*>(out_zq + m * D) + q * 16;
    float sum = 0.f;
#pragma unroll
    for (int e = 0; e < 16; ++e) {
      float4 cv = cq[e];
      float4 zv = zr[e];
      float dx = cv.x - zv.x, dy = cv.y - zv.y, dz = cv.z - zv.z, dw = cv.w - zv.w;
      float4 st;
      st.x = zv.x + dx; st.y = zv.y + dy; st.z = zv.z + dz; st.w = zv.w + dw;
      o4[e] = st;
      sum = fmaf(dx, dx, sum); sum = fmaf(dy, dy, sum);
      sum = fmaf(dz, dz, sum); sum = fmaf(dw, dw, sum);
    }
    sum += __shfl_xor(sum, 1, 64);
    if (q == 0) {
      float lv = sum * 0.0078125f;   // /128
      out_q[m]  = lv;
      out_iF[m] = (float)idx;
    }
  }
}

// ---------------- kernel 2: FULL RESCAN via cbT — also rewrites z_q/loss/idx ----------
__global__ __launch_bounds__(256, 4) void vq_rescan_cbT(
    const float* __restrict__ z, const float* __restrict__ cb,
    const float4* __restrict__ cbT4, const float* __restrict__ Cn,
    const int* __restrict__ cnt, const int* __restrict__ list,
    float* __restrict__ out_zq, float* __restrict__ out_q,
    float* __restrict__ out_iF) {
  __shared__ __align__(16) float Zs[D];
  __shared__ float sRed[256];
  __shared__ int   iRed[256];
  const int t = threadIdx.x;
  int n = *cnt; if (n > M_TOTAL - 1) n = M_TOTAL - 1;

  for (int it = blockIdx.x; it < n; it += gridDim.x) {
    const int row = list[it];
    if (t < 32) {
      reinterpret_cast<float4*>(Zs)[t] =
          reinterpret_cast<const float4*>(z + (size_t)row * D)[t];
    }
    __syncthreads();

    float a0 = 0.f, a1 = 0.f, a2 = 0.f, a3 = 0.f;
#pragma unroll 8
    for (int d = 0; d < D; ++d) {
      float  zv = Zs[d];                 // LDS broadcast
      float4 cv = cbT4[(d << 8) + t];    // lane-contiguous, L2-hit
      a0 = fmaf(zv, cv.x, a0);
      a1 = fmaf(zv, cv.y, a1);
      a2 = fmaf(zv, cv.z, a2);
      a3 = fmaf(zv, cv.w, a3);
    }
    const float A = np_norm128(Zs);

    const int kb = t * 4;
    float bd = 3.402823466e+38f; int bi = 0;
    {  // ascending k, strict <: numpy first-occurrence
      float d0 = __fadd_rn(__fsub_rn(A, __fmul_rn(2.0f, a0)), Cn[kb + 0]);
      float d1 = __fadd_rn(__fsub_rn(A, __fmul_rn(2.0f, a1)), Cn[kb + 1]);
      float d2 = __fadd_rn(__fsub_rn(A, __fmul_rn(2.0f, a2)), Cn[kb + 2]);
      float d3 = __fadd_rn(__fsub_rn(A, __fmul_rn(2.0f, a3)), Cn[kb + 3]);
      if (d0 < bd) { bd = d0; bi = kb + 0; }
      if (d1 < bd) { bd = d1; bi = kb + 1; }
      if (d2 < bd) { bd = d2; bi = kb + 2; }
      if (d3 < bd) { bd = d3; bi = kb + 3; }
    }
    sRed[t] = bd; iRed[t] = bi;
    __syncthreads();
    for (int w = 128; w > 0; w >>= 1) {
      if (t < w) {
        float o = sRed[t + w]; int oi = iRed[t + w];
        if (o < sRed[t] || (o == sRed[t] && oi < iRed[t])) { sRed[t] = o; iRed[t] = oi; }
      }
      __syncthreads();
    }
    // rewrite this row's outputs with the exact winner
    const int win = iRed[0];
    if (t < 32) {
      float4 zv = reinterpret_cast<const float4*>(Zs)[t];
      float4 cv = reinterpret_cast<const float4*>(cb + (size_t)win * D)[t];
      float dx = cv.x - zv.x, dy = cv.y - zv.y, dz = cv.z - zv.z, dw = cv.w - zv.w;
      float4 st;
      st.x = zv.x + dx; st.y = zv.y + dy; st.z = zv.z + dz; st.w = zv.w + dw;
      reinterpret_cast<float4*>(out_zq + (size_t)row * D)[t] = st;
      float sq = fmaf(dx, dx, fmaf(dy, dy, fmaf(dz, dz, dw * dw)));
      sq += __shfl_xor(sq, 1, 64);  sq += __shfl_xor(sq, 2, 64);
      sq += __shfl_xor(sq, 4, 64);  sq += __shfl_xor(sq, 8, 64);
      sq += __shfl_xor(sq, 16, 64);
      if (t == 0) {
        out_q[row]  = sq * 0.0078125f;
        out_iF[row] = (float)win;
      }
    }
    __syncthreads();   // protect Zs before next iteration
  }
}

// ---------------- kernel 3: commit_loss = quant_loss (after rescan; frees out2 scratch)
__global__ void vq_copy(const float* __restrict__ q, float* __restrict__ c) {
  int m = blockIdx.x * 256 + threadIdx.x;
  c[m] = q[m];
}

// ---------------- FALLBACK main: R4 kernel verbatim (validated, ~320 us) ---------------
__global__ __launch_bounds__(256) void vq_main_fp32(
    const float* __restrict__ z, const float* __restrict__ cb,
    const float* __restrict__ Cn,
    float* __restrict__ out_zq, float* __restrict__ out_q,
    float* __restrict__ out_c, float* __restrict__ out_i) {
  __shared__ float Zt[64 * D];
  __shared__ float Ct[64 * D];
  __shared__ float Arow[64];
  __shared__ int   idxArr[64];

  const int t  = threadIdx.x;
  const int ty = t >> 4;
  const int tx = t & 15;
  const int baseRow = blockIdx.x * 64;

  for (int s = t; s < 64 * (D / 4); s += 256) {
    int r = s >> 5, d4 = s & 31;
    float4 v = reinterpret_cast<const float4*>(z)[(size_t)(baseRow + r) * (D / 4) + d4];
    int colx = d4 ^ (r & 7);
    *reinterpret_cast<float4*>(&Zt[r * D + colx * 4]) = v;
  }
  __syncthreads();

  if (t < 64) {
    const int rs = t & 7;
    float r8[8];
#pragma unroll
    for (int j = 0; j < 8; ++j) {
      float v = Zt[t * D + (((j >> 2) ^ rs) << 2) + (j & 3)];
      r8[j] = __fmul_rn(v, v);
    }
    for (int i = 8; i < D; i += 8) {
#pragma unroll
      for (int j = 0; j < 8; ++j) {
        int d = i + j;
        float v = Zt[t * D + (((d >> 2) ^ rs) << 2) + (d & 3)];
        r8[j] = __fadd_rn(r8[j], __fmul_rn(v, v));
      }
    }
    Arow[t] = __fadd_rn(__fadd_rn(__fadd_rn(r8[0], r8[1]), __fadd_rn(r8[2], r8[3])),
                        __fadd_rn(__fadd_rn(r8[4], r8[5]), __fadd_rn(r8[6], r8[7])));
  }

  float s1[4]; int i1[4];
#pragma unroll
  for (int i = 0; i < 4; ++i) { s1[i] = 3.402823466e+38f; i1[i] = 0; }

  const int zsw = ty & 7;
  const int csw = tx & 7;

  for (int kt = 0; kt < 16; ++kt) {
    __syncthreads();
    for (int s = t; s < 64 * (D / 4); s += 256) {
      int r = s >> 5, d4 = s & 31;
      float4 v = reinterpret_cast<const float4*>(cb)[(size_t)(kt * 64 + r) * (D / 4) + d4];
      int colx = d4 ^ (r & 7);
      *reinterpret_cast<float4*>(&Ct[r * D + colx * 4]) = v;
    }
    __syncthreads();

    float acc[4][4];
#pragma unroll
    for (int i = 0; i < 4; ++i)
#pragma unroll
      for (int j = 0; j < 4; ++j) acc[i][j] = 0.f;

    for (int d4 = 0; d4 < 32; ++d4) {
      float4 za[4], cv[4];
      int zc = (d4 ^ zsw) * 4;
      int cc = (d4 ^ csw) * 4;
#pragma unroll
      for (int i = 0; i < 4; ++i)
        za[i] = *reinterpret_cast<const float4*>(&Zt[(ty + 16 * i) * D + zc]);
#pragma unroll
      for (int j = 0; j < 4; ++j)
        cv[j] = *reinterpret_cast<const float4*>(&Ct[(tx + 16 * j) * D + cc]);
#pragma unroll
      for (int i = 0; i < 4; ++i)
#pragma unroll
        for (int j = 0; j < 4; ++j) {
          acc[i][j] = fmaf(za[i].x, cv[j].x, acc[i][j]);
          acc[i][j] = fmaf(za[i].y, cv[j].y, acc[i][j]);
          acc[i][j] = fmaf(za[i].z, cv[j].z, acc[i][j]);
          acc[i][j] = fmaf(za[i].w, cv[j].w, acc[i][j]);
        }
    }

    float ch[4]; int kg[4];
#pragma unroll
    for (int j = 0; j < 4; ++j) {
      kg[j] = kt * 64 + tx + 16 * j;
      ch[j] = Cn[kg[j]];
    }
#pragma unroll
    for (int i = 0; i < 4; ++i) {
      float a = Arow[ty + 16 * i];
#pragma unroll
      for (int j = 0; j < 4; ++j) {
        float dist = __fadd_rn(__fsub_rn(a, __fmul_rn(2.0f, acc[i][j])), ch[j]);
        if (dist < s1[i]) { s1[i] = dist; i1[i] = kg[j]; }
      }
    }
  }

#pragma unroll
  for (int m = 1; m < 16; m <<= 1) {
#pragma unroll
    for (int i = 0; i < 4; ++i) {
      float os = __shfl_xor(s1[i], m, 64);
      int   oi = __shfl_xor(i1[i], m, 64);
      if (os < s1[i] || (os == s1[i] && oi < i1[i])) { s1[i] = os; i1[i] = oi; }
    }
  }

  if (tx == 0) {
#pragma unroll
    for (int i = 0; i < 4; ++i) idxArr[ty + 16 * i] = i1[i];
  }
  __syncthreads();

  {
    int r = t >> 2, q = t & 3;
    int idx = idxArr[r];
    size_t m = (size_t)baseRow + r;
    const float4* cq = reinterpret_cast<const float4*>(cb + (size_t)idx * D);
    const float4* zr = reinterpret_cast<const float4*>(z + m * D);
    float4*       o4 = reinterpret_cast<float4*>(out_zq + m * D);
    float sum = 0.f;
#pragma unroll
    for (int e = 0; e < 8; ++e) {
      int d4 = q * 8 + e;
      float4 cv = cq[d4];
      float4 zv = zr[d4];
      float dx = cv.x - zv.x, dy = cv.y - zv.y, dz = cv.z - zv.z, dw = cv.w - zv.w;
      float4 st;
      st.x = zv.x + dx; st.y = zv.y + dy; st.z = zv.z + dz; st.w = zv.w + dw;
      o4[d4] = st;
      sum = fmaf(dx, dx, sum); sum = fmaf(dy, dy, sum);
      sum = fmaf(dz, dz, sum); sum = fmaf(dw, dw, sum);
    }
    sum += __shfl_xor(sum, 1, 64);
    sum += __shfl_xor(sum, 2, 64);
    if (q == 0) {
      float lv = sum * 0.0078125f;
      out_q[m] = lv;
      out_c[m] = lv;
      out_i[m] = (float)idx;
    }
  }
}

extern "C" void kernel_launch(void* const* d_in, const int* in_sizes, int n_in,
                              void* d_out, int out_size, void* d_ws, size_t ws_size,
                              hipStream_t stream) {
  const float* z  = (const float*)d_in[0];   // [16,4096,128] fp32
  const float* cb = (const float*)d_in[1];   // [1024,128] fp32

  float* out0 = (float*)d_out;               // z_q_ste  [M,128]
  float* out1 = out0 + (size_t)M_TOTAL * D;  // quant_loss [M]
  float* out2 = out1 + M_TOTAL;              // commit_loss [M]
  float* out3 = out2 + M_TOTAL;              // indices (as float) [M]

  float* Cn = (float*)((char*)d_ws + WS_CN);
  // cnt/list live in out2 during score+rescan; vq_copy then writes commit_loss there.
  int* cnt  = (int*)out2;
  int* list = (int*)out2 + 1;

  if (ws_size >= WS_REQ2) {
    short*  Bh   = (short*)((char*)d_ws + WS_BH);
    short*  Bl   = (short*)((char*)d_ws + WS_BL);
    float4* cbT4 = (float4*)((char*)d_ws + WS_CBT);
    vq_prep_all<<<196, 256, 0, stream>>>(cb, Cn, cnt, Bh, Bl, cbT4);
    vq_score<<<M_TOTAL / BM, 256, 0, stream>>>(z, cb, Cn, Bh, Bl,
                                               out0, out1, out3, cnt, list);
    vq_rescan_cbT<<<1024, 256, 0, stream>>>(z, cb, cbT4, Cn, cnt, list,
                                            out0, out1, out3);
    vq_copy<<<M_TOTAL / 256, 256, 0, stream>>>(out1, out2);
  } else {
    vq_prep_all<<<4, 256, 0, stream>>>(cb, Cn, cnt, nullptr, nullptr, nullptr);
    vq_main_fp32<<<M_TOTAL / 64, 256, 0, stream>>>(z, cb, Cn, out0, out1, out2, out3);
  }
}

// Round 25
// 106.862 us; speedup vs baseline: 1.6026x; 1.0338x over previous
//
#include <hip/hip_runtime.h>
#include <hip/hip_bf16.h>

namespace {
constexpr int D       = 128;
constexpr int K       = 1024;
constexpr int M_TOTAL = 65536;   // 16 * 4096
constexpr int BM      = 128;     // rows per score-block: 4 waves x 32 rows
constexpr int NCT     = K / 16;  // 64 code-tiles of 16 codes
constexpr float TAU   = 5.0e-5f; // > 2*(scorer err) + 2*(numpy quantization span)
// d_ws layout
constexpr size_t WS_CN   = 0;                    // float[1024]     (4 KB)
constexpr size_t WS_BH   = 4096;                 // short[131072]   (256 KB)
constexpr size_t WS_BL   = 4096 + 262144;        // short[131072]   (256 KB)
constexpr size_t WS_REQ  = 4096 + 2 * 262144;    // 528,384 B (confirmed, R11-R24)
constexpr size_t WS_CBT  = WS_REQ;               // float4[32768]   (512 KB)
constexpr size_t WS_REQ2 = WS_REQ + 524288;      // 1,052,672 B (confirmed, R19-R24)
}

typedef short bf16x8 __attribute__((ext_vector_type(8)));
typedef float f32x4  __attribute__((ext_vector_type(4)));

static __device__ __forceinline__ unsigned short bfbits(float x) {
  __hip_bfloat16 h = __float2bfloat16(x);   // RNE
  return *reinterpret_cast<unsigned short*>(&h);
}
static __device__ __forceinline__ float bfhi2f(unsigned short h) {
  return __uint_as_float(((unsigned)h) << 16);
}
static __device__ __forceinline__ void split8(float4 a, float4 b,
                                              bf16x8& ph, bf16x8& pl) {
  float v[8] = {a.x, a.y, a.z, a.w, b.x, b.y, b.z, b.w};
#pragma unroll
  for (int e = 0; e < 8; ++e) {
    unsigned short h = bfbits(v[e]);
    unsigned short l = bfbits(v[e] - bfhi2f(h));
    ph[e] = (short)h;
    pl[e] = (short)l;
  }
}
// numpy pairwise-8 row norm of 128 consecutive floats (R4-validated, bit-exact)
static __device__ __forceinline__ float np_norm128(const float* p) {
  float r8[8];
#pragma unroll
  for (int j = 0; j < 8; ++j) r8[j] = __fmul_rn(p[j], p[j]);
  for (int i = 8; i < D; i += 8) {
#pragma unroll
    for (int j = 0; j < 8; ++j)
      r8[j] = __fadd_rn(r8[j], __fmul_rn(p[i + j], p[i + j]));
  }
  return __fadd_rn(__fadd_rn(__fadd_rn(r8[0], r8[1]), __fadd_rn(r8[2], r8[3])),
                   __fadd_rn(__fadd_rn(r8[4], r8[5]), __fadd_rn(r8[6], r8[7])));
}

// ---------------- merged prep: Cn + cnt=0 | bf16 planes | transposed codebook ---------
__global__ void vq_prep_all(const float* __restrict__ cb, float* __restrict__ Cn,
                            int* __restrict__ cnt,
                            short* __restrict__ Bh, short* __restrict__ Bl,
                            float4* __restrict__ cbT4) {
  const int b = blockIdx.x, t = threadIdx.x;
  if (b < 4) {
    int k = b * 256 + t;
    if (b == 0 && t == 0) *cnt = 0;
    if (k < K) Cn[k] = np_norm128(cb + (size_t)k * D);
  } else if (b < 68) {
    int g = (b - 4) * 256 + t;                  // 0 .. 16383
    int code = (g >> 8) * 16 + (g & 15);
    int d0   = ((g >> 6) & 3) * 32 + ((g >> 4) & 3) * 8;
    const float* p = cb + (size_t)code * D + d0;
    float4 a = *reinterpret_cast<const float4*>(p);
    float4 bb = *reinterpret_cast<const float4*>(p + 4);
    bf16x8 ph, pl;
    split8(a, bb, ph, pl);
    *reinterpret_cast<bf16x8*>(Bh + (size_t)g * 8) = ph;
    *reinterpret_cast<bf16x8*>(Bl + (size_t)g * 8) = pl;
  } else {
    int g = (b - 68) * 256 + t;                 // 0 .. 32767
    int d = g >> 8, tt = g & 255;
    float4 v;
    v.x = cb[(size_t)(4 * tt + 0) * D + d];
    v.y = cb[(size_t)(4 * tt + 1) * D + d];
    v.z = cb[(size_t)(4 * tt + 2) * D + d];
    v.w = cb[(size_t)(4 * tt + 3) * D + d];
    cbT4[g] = v;
  }
}

// ---------------- kernel 1: SCORE — 4 slots x 2 tiles/slot + flat-coalesced fused epi --
__global__ __launch_bounds__(256, 2) void vq_score(
    const float* __restrict__ z, const float* __restrict__ cb,
    const float* __restrict__ Cn,
    const short* __restrict__ BhG, const short* __restrict__ BlG,
    float* __restrict__ out_zq, float* __restrict__ out_q,
    float* __restrict__ out_iF, int* __restrict__ cnt, int* __restrict__ list) {
  __shared__ __align__(16) short Bbuf[4][2][8][512];  // 4 slots x 2 tiles x 8 KB = 64 KB
  __shared__ float CnS[K];                             // 4 KB
  __shared__ int   idxW[4][32];                        // per-wave row indices

  const int t    = threadIdx.x;
  const int wave = t >> 6;
  const int lane = t & 63;
  const int col  = lane & 15;
  const int baseRow = blockIdx.x * BM;

  for (int i = t; i < K; i += 256) CnS[i] = Cn[i];

  bf16x8 ah[2][4], al[2][4];
#pragma unroll
  for (int set = 0; set < 2; ++set) {
    const float* zL = z + (size_t)(baseRow + wave * 32 + set * 16 + col) * D + (lane >> 4) * 8;
#pragma unroll
    for (int ks = 0; ks < 4; ++ks) {
      float4 a = *reinterpret_cast<const float4*>(zL + ks * 32);
      float4 b = *reinterpret_cast<const float4*>(zL + ks * 32 + 4);
      split8(a, b, ah[set][ks], al[set][ks]);
    }
  }

  float s1[2][4], s2[2][4]; int i1[2][4];
#pragma unroll
  for (int s = 0; s < 2; ++s)
#pragma unroll
    for (int i = 0; i < 4; ++i) {
      s1[s][i] = 3.402823466e+38f; s2[s][i] = 3.402823466e+38f; i1[s][i] = 0;
    }

  // stage tiles ct_, ct_+1 into slot sl_ (4 loads/thread: 2 tiles x 2 chunks)
#define STAGE2(ct_, sl_)                                                            \
  { _Pragma("unroll")                                                               \
    for (int i_ = 0; i_ < 4; ++i_) {                                                \
      int ti_ = i_ >> 1;                                                            \
      int c_  = wave * 2 + (i_ & 1);                                                \
      int p_  = c_ >> 2, ks_ = c_ & 3;                                              \
      const short* gsrc_ = (p_ ? BlG : BhG) +                                       \
                           (size_t)((((ct_) + ti_) * 4 + ks_) * 64 + lane) * 8;     \
      __builtin_amdgcn_global_load_lds(                                             \
          (const __attribute__((address_space(1))) void*)gsrc_,                     \
          (__attribute__((address_space(3))) void*)&Bbuf[sl_][ti_][c_][0], 16, 0, 0); \
    } }

#define COMP(sl_, ti_, ct_)                                                         \
  { bf16x8 bh_c[4], bl_c[4];                                                        \
    _Pragma("unroll")                                                               \
    for (int ks_ = 0; ks_ < 4; ++ks_) {                                             \
      bh_c[ks_] = *reinterpret_cast<const bf16x8*>(&Bbuf[sl_][ti_][ks_][lane * 8]);      \
      bl_c[ks_] = *reinterpret_cast<const bf16x8*>(&Bbuf[sl_][ti_][4 + ks_][lane * 8]);  \
    }                                                                               \
    const int code_ = (ct_) * 16 + col;                                             \
    const float cn_ = CnS[code_];                                                   \
    __builtin_amdgcn_s_setprio(1);                                                  \
    _Pragma("unroll")                                                               \
    for (int set_ = 0; set_ < 2; ++set_) {                                          \
      f32x4 aA = (f32x4){0.f,0.f,0.f,0.f};                                          \
      f32x4 aB = (f32x4){0.f,0.f,0.f,0.f};                                          \
      f32x4 aC = (f32x4){0.f,0.f,0.f,0.f};                                          \
      _Pragma("unroll")                                                             \
      for (int ks_ = 0; ks_ < 4; ++ks_) {                                           \
        aA = __builtin_amdgcn_mfma_f32_16x16x32_bf16(ah[set_][ks_], bh_c[ks_], aA, 0,0,0); \
        aB = __builtin_amdgcn_mfma_f32_16x16x32_bf16(ah[set_][ks_], bl_c[ks_], aB, 0,0,0); \
        aC = __builtin_amdgcn_mfma_f32_16x16x32_bf16(al[set_][ks_], bh_c[ks_], aC, 0,0,0); \
      }                                                                             \
      _Pragma("unroll")                                                             \
      for (int reg_ = 0; reg_ < 4; ++reg_) {                                        \
        float S = fmaf(-2.0f, (aA[reg_] + aB[reg_]) + aC[reg_], cn_);               \
        if (S < s1[set_][reg_]) { s2[set_][reg_] = s1[set_][reg_];                  \
                                  s1[set_][reg_] = S; i1[set_][reg_] = code_; }     \
        else if (S < s2[set_][reg_]) { s2[set_][reg_] = S; }                        \
      }                                                                             \
    }                                                                               \
    __builtin_amdgcn_s_setprio(0); }

  // phase: vmcnt(8) = 2 newer slots stay in flight; barrier; 2 tiles; prefetch 2 tiles
#define PHASE(g_, sl_)                                                              \
  { asm volatile("s_waitcnt vmcnt(8)" ::: "memory");                                \
    __builtin_amdgcn_s_barrier();                                                   \
    __builtin_amdgcn_sched_barrier(0);                                              \
    COMP(sl_, 0, 2 * (g_));                                                         \
    COMP(sl_, 1, 2 * (g_) + 1);                                                     \
    STAGE2((2 * (g_) + 6) & 63, ((sl_) + 3) & 3); }

  __syncthreads();   // CnS visible
  STAGE2(0, 0); STAGE2(2, 1); STAGE2(4, 2);   // 12 loads/thread in flight
  for (int g = 0; g < NCT / 2; g += 4) {
    PHASE(g + 0, 0);
    PHASE(g + 1, 1);
    PHASE(g + 2, 2);
    PHASE(g + 3, 3);
  }
#undef PHASE
#undef STAGE2
#undef COMP

  // cross-lane (16-col group) min1/min2 merge
#pragma unroll
  for (int m = 1; m < 16; m <<= 1) {
#pragma unroll
    for (int set = 0; set < 2; ++set)
#pragma unroll
      for (int reg = 0; reg < 4; ++reg) {
        float os1 = __shfl_xor(s1[set][reg], m, 64);
        float os2 = __shfl_xor(s2[set][reg], m, 64);
        int   oi  = __shfl_xor(i1[set][reg], m, 64);
        if (os1 < s1[set][reg]) {
          s2[set][reg] = fminf(s1[set][reg], os2);
          s1[set][reg] = os1; i1[set][reg] = oi;
        } else {
          s2[set][reg] = fminf(s2[set][reg], os1);
        }
      }
  }

  // idx -> per-wave LDS + fused hard-row flagging (wave-local)
  if (col == 0) {
#pragma unroll
    for (int set = 0; set < 2; ++set)
#pragma unroll
      for (int reg = 0; reg < 4; ++reg) {
        int wr = set * 16 + (lane >> 4) * 4 + reg;     // 0..31 within wave
        idxW[wave][wr] = i1[set][reg];
        if (s2[set][reg] - s1[set][reg] < TAU) {
          int p = atomicAdd(cnt, 1);
          if (p < M_TOTAL - 1) list[p] = (int)(baseRow + wave * 32 + wr);
        }
      }
  }
  // same-wave LDS write->read: in-order per wave

  // fused epilogue, FLAT-COALESCED: wave's 32 rows = 1024 float4; lane handles
  // flat idx lane+64*it -> per instruction lanes 0-31 cover row 2*it fully,
  // lanes 32-63 row 2*it+1 (contiguous 1KB loads/stores; no partial-line RMW).
  {
    const float* zW  = z      + ((size_t)baseRow + wave * 32) * D;
    float*       oW  = out_zq + ((size_t)baseRow + wave * 32) * D;
#pragma unroll
    for (int it = 0; it < 16; ++it) {
      const int flat = lane + 64 * it;     // 0..1023
      const int r    = flat >> 5;          // row within wave (uniform per 32-lane half)
      const int d4   = flat & 31;
      const int idx  = idxW[wave][r];      // broadcast within half
      float4 cv = reinterpret_cast<const float4*>(cb + (size_t)idx * D)[d4];
      float4 zv = reinterpret_cast<const float4*>(zW)[flat];
      float dx = cv.x - zv.x, dy = cv.y - zv.y, dz = cv.z - zv.z, dw = cv.w - zv.w;
      float4 st;
      st.x = zv.x + dx; st.y = zv.y + dy; st.z = zv.z + dz; st.w = zv.w + dw;
      reinterpret_cast<float4*>(oW)[flat] = st;
      float sq = fmaf(dx, dx, fmaf(dy, dy, fmaf(dz, dz, dw * dw)));
      sq += __shfl_xor(sq, 1, 64);  sq += __shfl_xor(sq, 2, 64);
      sq += __shfl_xor(sq, 4, 64);  sq += __shfl_xor(sq, 8, 64);
      sq += __shfl_xor(sq, 16, 64);                       // reduce within 32-lane half
      if ((lane & 31) == 0) {
        size_t m = (size_t)baseRow + wave * 32 + r;
        out_q[m]  = sq * 0.0078125f;   // /128
        out_iF[m] = (float)idx;
      }
    }
  }
}

// ---------------- kernel 2: FULL RESCAN via cbT — also rewrites z_q/loss/idx ----------
__global__ __launch_bounds__(256, 4) void vq_rescan_cbT(
    const float* __restrict__ z, const float* __restrict__ cb,
    const float4* __restrict__ cbT4, const float* __restrict__ Cn,
    const int* __restrict__ cnt, const int* __restrict__ list,
    float* __restrict__ out_zq, float* __restrict__ out_q,
    float* __restrict__ out_iF) {
  __shared__ __align__(16) float Zs[D];
  __shared__ float sRed[256];
  __shared__ int   iRed[256];
  const int t = threadIdx.x;
  int n = *cnt; if (n > M_TOTAL - 1) n = M_TOTAL - 1;

  for (int it = blockIdx.x; it < n; it += gridDim.x) {
    const int row = list[it];
    if (t < 32) {
      reinterpret_cast<float4*>(Zs)[t] =
          reinterpret_cast<const float4*>(z + (size_t)row * D)[t];
    }
    __syncthreads();

    float a0 = 0.f, a1 = 0.f, a2 = 0.f, a3 = 0.f;
#pragma unroll 8
    for (int d = 0; d < D; ++d) {
      float  zv = Zs[d];                 // LDS broadcast
      float4 cv = cbT4[(d << 8) + t];    // lane-contiguous, L2-hit
      a0 = fmaf(zv, cv.x, a0);
      a1 = fmaf(zv, cv.y, a1);
      a2 = fmaf(zv, cv.z, a2);
      a3 = fmaf(zv, cv.w, a3);
    }
    const float A = np_norm128(Zs);

    const int kb = t * 4;
    float bd = 3.402823466e+38f; int bi = 0;
    {  // ascending k, strict <: numpy first-occurrence
      float d0 = __fadd_rn(__fsub_rn(A, __fmul_rn(2.0f, a0)), Cn[kb + 0]);
      float d1 = __fadd_rn(__fsub_rn(A, __fmul_rn(2.0f, a1)), Cn[kb + 1]);
      float d2 = __fadd_rn(__fsub_rn(A, __fmul_rn(2.0f, a2)), Cn[kb + 2]);
      float d3 = __fadd_rn(__fsub_rn(A, __fmul_rn(2.0f, a3)), Cn[kb + 3]);
      if (d0 < bd) { bd = d0; bi = kb + 0; }
      if (d1 < bd) { bd = d1; bi = kb + 1; }
      if (d2 < bd) { bd = d2; bi = kb + 2; }
      if (d3 < bd) { bd = d3; bi = kb + 3; }
    }
    sRed[t] = bd; iRed[t] = bi;
    __syncthreads();
    for (int w = 128; w > 0; w >>= 1) {
      if (t < w) {
        float o = sRed[t + w]; int oi = iRed[t + w];
        if (o < sRed[t] || (o == sRed[t] && oi < iRed[t])) { sRed[t] = o; iRed[t] = oi; }
      }
      __syncthreads();
    }
    // rewrite this row's outputs with the exact winner
    const int win = iRed[0];
    if (t < 32) {
      float4 zv = reinterpret_cast<const float4*>(Zs)[t];
      float4 cv = reinterpret_cast<const float4*>(cb + (size_t)win * D)[t];
      float dx = cv.x - zv.x, dy = cv.y - zv.y, dz = cv.z - zv.z, dw = cv.w - zv.w;
      float4 st;
      st.x = zv.x + dx; st.y = zv.y + dy; st.z = zv.z + dz; st.w = zv.w + dw;
      reinterpret_cast<float4*>(out_zq + (size_t)row * D)[t] = st;
      float sq = fmaf(dx, dx, fmaf(dy, dy, fmaf(dz, dz, dw * dw)));
      sq += __shfl_xor(sq, 1, 64);  sq += __shfl_xor(sq, 2, 64);
      sq += __shfl_xor(sq, 4, 64);  sq += __shfl_xor(sq, 8, 64);
      sq += __shfl_xor(sq, 16, 64);
      if (t == 0) {
        out_q[row]  = sq * 0.0078125f;
        out_iF[row] = (float)win;
      }
    }
    __syncthreads();   // protect Zs before next iteration
  }
}

// ---------------- kernel 3: commit_loss = quant_loss (after rescan; frees out2 scratch)
__global__ void vq_copy(const float* __restrict__ q, float* __restrict__ c) {
  int m = blockIdx.x * 256 + threadIdx.x;
  c[m] = q[m];
}

// ---------------- FALLBACK main: R4 kernel verbatim (validated, ~320 us) ---------------
__global__ __launch_bounds__(256) void vq_main_fp32(
    const float* __restrict__ z, const float* __restrict__ cb,
    const float* __restrict__ Cn,
    float* __restrict__ out_zq, float* __restrict__ out_q,
    float* __restrict__ out_c, float* __restrict__ out_i) {
  __shared__ float Zt[64 * D];
  __shared__ float Ct[64 * D];
  __shared__ float Arow[64];
  __shared__ int   idxArr[64];

  const int t  = threadIdx.x;
  const int ty = t >> 4;
  const int tx = t & 15;
  const int baseRow = blockIdx.x * 64;

  for (int s = t; s < 64 * (D / 4); s += 256) {
    int r = s >> 5, d4 = s & 31;
    float4 v = reinterpret_cast<const float4*>(z)[(size_t)(baseRow + r) * (D / 4) + d4];
    int colx = d4 ^ (r & 7);
    *reinterpret_cast<float4*>(&Zt[r * D + colx * 4]) = v;
  }
  __syncthreads();

  if (t < 64) {
    const int rs = t & 7;
    float r8[8];
#pragma unroll
    for (int j = 0; j < 8; ++j) {
      float v = Zt[t * D + (((j >> 2) ^ rs) << 2) + (j & 3)];
      r8[j] = __fmul_rn(v, v);
    }
    for (int i = 8; i < D; i += 8) {
#pragma unroll
      for (int j = 0; j < 8; ++j) {
        int d = i + j;
        float v = Zt[t * D + (((d >> 2) ^ rs) << 2) + (d & 3)];
        r8[j] = __fadd_rn(r8[j], __fmul_rn(v, v));
      }
    }
    Arow[t] = __fadd_rn(__fadd_rn(__fadd_rn(r8[0], r8[1]), __fadd_rn(r8[2], r8[3])),
                        __fadd_rn(__fadd_rn(r8[4], r8[5]), __fadd_rn(r8[6], r8[7])));
  }

  float s1[4]; int i1[4];
#pragma unroll
  for (int i = 0; i < 4; ++i) { s1[i] = 3.402823466e+38f; i1[i] = 0; }

  const int zsw = ty & 7;
  const int csw = tx & 7;

  for (int kt = 0; kt < 16; ++kt) {
    __syncthreads();
    for (int s = t; s < 64 * (D / 4); s += 256) {
      int r = s >> 5, d4 = s & 31;
      float4 v = reinterpret_cast<const float4*>(cb)[(size_t)(kt * 64 + r) * (D / 4) + d4];
      int colx = d4 ^ (r & 7);
      *reinterpret_cast<float4*>(&Ct[r * D + colx * 4]) = v;
    }
    __syncthreads();

    float acc[4][4];
#pragma unroll
    for (int i = 0; i < 4; ++i)
#pragma unroll
      for (int j = 0; j < 4; ++j) acc[i][j] = 0.f;

    for (int d4 = 0; d4 < 32; ++d4) {
      float4 za[4], cv[4];
      int zc = (d4 ^ zsw) * 4;
      int cc = (d4 ^ csw) * 4;
#pragma unroll
      for (int i = 0; i < 4; ++i)
        za[i] = *reinterpret_cast<const float4*>(&Zt[(ty + 16 * i) * D + zc]);
#pragma unroll
      for (int j = 0; j < 4; ++j)
        cv[j] = *reinterpret_cast<const float4*>(&Ct[(tx + 16 * j) * D + cc]);
#pragma unroll
      for (int i = 0; i < 4; ++i)
#pragma unroll
        for (int j = 0; j < 4; ++j) {
          acc[i][j] = fmaf(za[i].x, cv[j].x, acc[i][j]);
          acc[i][j] = fmaf(za[i].y, cv[j].y, acc[i][j]);
          acc[i][j] = fmaf(za[i].z, cv[j].z, acc[i][j]);
          acc[i][j] = fmaf(za[i].w, cv[j].w, acc[i][j]);
        }
    }

    float ch[4]; int kg[4];
#pragma unroll
    for (int j = 0; j < 4; ++j) {
      kg[j] = kt * 64 + tx + 16 * j;
      ch[j] = Cn[kg[j]];
    }
#pragma unroll
    for (int i = 0; i < 4; ++i) {
      float a = Arow[ty + 16 * i];
#pragma unroll
      for (int j = 0; j < 4; ++j) {
        float dist = __fadd_rn(__fsub_rn(a, __fmul_rn(2.0f, acc[i][j])), ch[j]);
        if (dist < s1[i]) { s1[i] = dist; i1[i] = kg[j]; }
      }
    }
  }

#pragma unroll
  for (int m = 1; m < 16; m <<= 1) {
#pragma unroll
    for (int i = 0; i < 4; ++i) {
      float os = __shfl_xor(s1[i], m, 64);
      int   oi = __shfl_xor(i1[i], m, 64);
      if (os < s1[i] || (os == s1[i] && oi < i1[i])) { s1[i] = os; i1[i] = oi; }
    }
  }

  if (tx == 0) {
#pragma unroll
    for (int i = 0; i < 4; ++i) idxArr[ty + 16 * i] = i1[i];
  }
  __syncthreads();

  {
    int r = t >> 2, q = t & 3;
    int idx = idxArr[r];
    size_t m = (size_t)baseRow + r;
    const float4* cq = reinterpret_cast<const float4*>(cb + (size_t)idx * D);
    const float4* zr = reinterpret_cast<const float4*>(z + m * D);
    float4*       o4 = reinterpret_cast<float4*>(out_zq + m * D);
    float sum = 0.f;
#pragma unroll
    for (int e = 0; e < 8; ++e) {
      int d4 = q * 8 + e;
      float4 cv = cq[d4];
      float4 zv = zr[d4];
      float dx = cv.x - zv.x, dy = cv.y - zv.y, dz = cv.z - zv.z, dw = cv.w - zv.w;
      float4 st;
      st.x = zv.x + dx; st.y = zv.y + dy; st.z = zv.z + dz; st.w = zv.w + dw;
      o4[d4] = st;
      sum = fmaf(dx, dx, sum); sum = fmaf(dy, dy, sum);
      sum = fmaf(dz, dz, sum); sum = fmaf(dw, dw, sum);
    }
    sum += __shfl_xor(sum, 1, 64);
    sum += __shfl_xor(sum, 2, 64);
    if (q == 0) {
      float lv = sum * 0.0078125f;
      out_q[m] = lv;
      out_c[m] = lv;
      out_i[m] = (float)idx;
    }
  }
}

extern "C" void kernel_launch(void* const* d_in, const int* in_sizes, int n_in,
                              void* d_out, int out_size, void* d_ws, size_t ws_size,
                              hipStream_t stream) {
  const float* z  = (const float*)d_in[0];   // [16,4096,128] fp32
  const float* cb = (const float*)d_in[1];   // [1024,128] fp32

  float* out0 = (float*)d_out;               // z_q_ste  [M,128]
  float* out1 = out0 + (size_t)M_TOTAL * D;  // quant_loss [M]
  float* out2 = out1 + M_TOTAL;              // commit_loss [M]
  float* out3 = out2 + M_TOTAL;              // indices (as float) [M]

  float* Cn = (float*)((char*)d_ws + WS_CN);
  // cnt/list live in out2 during score+rescan; vq_copy then writes commit_loss there.
  int* cnt  = (int*)out2;
  int* list = (int*)out2 + 1;

  if (ws_size >= WS_REQ2) {
    short*  Bh   = (short*)((char*)d_ws + WS_BH);
    short*  Bl   = (short*)((char*)d_ws + WS_BL);
    float4* cbT4 = (float4*)((char*)d_ws + WS_CBT);
    vq_prep_all<<<196, 256, 0, stream>>>(cb, Cn, cnt, Bh, Bl, cbT4);
    vq_score<<<M_TOTAL / BM, 256, 0, stream>>>(z, cb, Cn, Bh, Bl,
                                               out0, out1, out3, cnt, list);
    vq_rescan_cbT<<<1024, 256, 0, stream>>>(z, cb, cbT4, Cn, cnt, list,
                                            out0, out1, out3);
    vq_copy<<<M_TOTAL / 256, 256, 0, stream>>>(out1, out2);
  } else {
    vq_prep_all<<<4, 256, 0, stream>>>(cb, Cn, cnt, nullptr, nullptr, nullptr);
    vq_main_fp32<<<M_TOTAL / 64, 256, 0, stream>>>(z, cb, Cn, out0, out1, out2, out3);
  }
}

// Round 26
// 103.851 us; speedup vs baseline: 1.6491x; 1.0290x over previous
//
#include <hip/hip_runtime.h>
#include <hip/hip_bf16.h>

namespace {
constexpr int D       = 128;
constexpr int K       = 1024;
constexpr int M_TOTAL = 65536;   // 16 * 4096
constexpr int BM      = 64;      // rows per score-block: 4 waves x 16 rows -> grid 1024
constexpr int NCT     = K / 16;  // 64 code-tiles of 16 codes
constexpr float TAU   = 5.0e-5f; // > 2*(scorer err) + 2*(numpy quantization span)
// d_ws layout
constexpr size_t WS_CN   = 0;                    // float[1024]     (4 KB)
constexpr size_t WS_BH   = 4096;                 // short[131072]   (256 KB)
constexpr size_t WS_BL   = 4096 + 262144;        // short[131072]   (256 KB)
constexpr size_t WS_REQ  = 4096 + 2 * 262144;    // 528,384 B (confirmed, R11-R25)
constexpr size_t WS_CBT  = WS_REQ;               // float4[32768]   (512 KB)
constexpr size_t WS_REQ2 = WS_REQ + 524288;      // 1,052,672 B (confirmed, R19-R25)
}

typedef short bf16x8 __attribute__((ext_vector_type(8)));
typedef float f32x4  __attribute__((ext_vector_type(4)));

static __device__ __forceinline__ unsigned short bfbits(float x) {
  __hip_bfloat16 h = __float2bfloat16(x);   // RNE
  return *reinterpret_cast<unsigned short*>(&h);
}
static __device__ __forceinline__ float bfhi2f(unsigned short h) {
  return __uint_as_float(((unsigned)h) << 16);
}
static __device__ __forceinline__ void split8(float4 a, float4 b,
                                              bf16x8& ph, bf16x8& pl) {
  float v[8] = {a.x, a.y, a.z, a.w, b.x, b.y, b.z, b.w};
#pragma unroll
  for (int e = 0; e < 8; ++e) {
    unsigned short h = bfbits(v[e]);
    unsigned short l = bfbits(v[e] - bfhi2f(h));
    ph[e] = (short)h;
    pl[e] = (short)l;
  }
}
// numpy pairwise-8 row norm of 128 consecutive floats (R4-validated, bit-exact)
static __device__ __forceinline__ float np_norm128(const float* p) {
  float r8[8];
#pragma unroll
  for (int j = 0; j < 8; ++j) r8[j] = __fmul_rn(p[j], p[j]);
  for (int i = 8; i < D; i += 8) {
#pragma unroll
    for (int j = 0; j < 8; ++j)
      r8[j] = __fadd_rn(r8[j], __fmul_rn(p[i + j], p[i + j]));
  }
  return __fadd_rn(__fadd_rn(__fadd_rn(r8[0], r8[1]), __fadd_rn(r8[2], r8[3])),
                   __fadd_rn(__fadd_rn(r8[4], r8[5]), __fadd_rn(r8[6], r8[7])));
}

// ---------------- merged prep: Cn + cnt=0 | bf16 planes | transposed codebook ---------
__global__ void vq_prep_all(const float* __restrict__ cb, float* __restrict__ Cn,
                            int* __restrict__ cnt,
                            short* __restrict__ Bh, short* __restrict__ Bl,
                            float4* __restrict__ cbT4) {
  const int b = blockIdx.x, t = threadIdx.x;
  if (b < 4) {
    int k = b * 256 + t;
    if (b == 0 && t == 0) *cnt = 0;
    if (k < K) Cn[k] = np_norm128(cb + (size_t)k * D);
  } else if (b < 68) {
    int g = (b - 4) * 256 + t;                  // 0 .. 16383
    int code = (g >> 8) * 16 + (g & 15);
    int d0   = ((g >> 6) & 3) * 32 + ((g >> 4) & 3) * 8;
    const float* p = cb + (size_t)code * D + d0;
    float4 a = *reinterpret_cast<const float4*>(p);
    float4 bb = *reinterpret_cast<const float4*>(p + 4);
    bf16x8 ph, pl;
    split8(a, bb, ph, pl);
    *reinterpret_cast<bf16x8*>(Bh + (size_t)g * 8) = ph;
    *reinterpret_cast<bf16x8*>(Bl + (size_t)g * 8) = pl;
  } else {
    int g = (b - 68) * 256 + t;                 // 0 .. 32767
    int d = g >> 8, tt = g & 255;
    float4 v;
    v.x = cb[(size_t)(4 * tt + 0) * D + d];
    v.y = cb[(size_t)(4 * tt + 1) * D + d];
    v.z = cb[(size_t)(4 * tt + 2) * D + d];
    v.w = cb[(size_t)(4 * tt + 3) * D + d];
    cbT4[g] = v;
  }
}

// ---------------- kernel 1: SCORE — BM=64 (grid 1024 = 4 blocks/CU), R23 schedule ----
__global__ __launch_bounds__(256, 4) void vq_score(
    const float* __restrict__ z, const float* __restrict__ cb,
    const float* __restrict__ Cn,
    const short* __restrict__ BhG, const short* __restrict__ BlG,
    float* __restrict__ out_zq, float* __restrict__ out_q,
    float* __restrict__ out_iF, int* __restrict__ cnt, int* __restrict__ list) {
  __shared__ __align__(16) short Bbuf[4][8][512];   // 4 slots x 8 KB = 32 KB
  __shared__ float CnS[K];                           // 4 KB
  __shared__ int   idxW[4][16];                      // per-wave row indices

  const int t    = threadIdx.x;
  const int wave = t >> 6;
  const int lane = t & 63;
  const int col  = lane & 15;
  const int baseRow = blockIdx.x * BM;

  for (int i = t; i < K; i += 256) CnS[i] = Cn[i];

  // A fragments: this wave's 16 z-rows (1 set)
  bf16x8 ah[4], al[4];
  {
    const float* zL = z + (size_t)(baseRow + wave * 16 + col) * D + (lane >> 4) * 8;
#pragma unroll
    for (int ks = 0; ks < 4; ++ks) {
      float4 a = *reinterpret_cast<const float4*>(zL + ks * 32);
      float4 b = *reinterpret_cast<const float4*>(zL + ks * 32 + 4);
      split8(a, b, ah[ks], al[ks]);
    }
  }

  float s1[4], s2[4]; int i1[4];
#pragma unroll
  for (int i = 0; i < 4; ++i) {
    s1[i] = 3.402823466e+38f; s2[i] = 3.402823466e+38f; i1[i] = 0;
  }

#define STAGE(ct_, bi_)                                                             \
  { _Pragma("unroll")                                                               \
    for (int i_ = 0; i_ < 2; ++i_) {                                                \
      int c_  = wave * 2 + i_;                                                      \
      int p_  = c_ >> 2, ks_ = c_ & 3;                                              \
      const short* gsrc_ = (p_ ? BlG : BhG) +                                       \
                           (size_t)(((ct_) * 4 + ks_) * 64 + lane) * 8;             \
      __builtin_amdgcn_global_load_lds(                                             \
          (const __attribute__((address_space(1))) void*)gsrc_,                     \
          (__attribute__((address_space(3))) void*)&Bbuf[bi_][c_][0], 16, 0, 0);    \
    } }

#define COMP(bi_, ct_)                                                              \
  { bf16x8 bh_c[4], bl_c[4];                                                        \
    _Pragma("unroll")                                                               \
    for (int ks_ = 0; ks_ < 4; ++ks_) {                                             \
      bh_c[ks_] = *reinterpret_cast<const bf16x8*>(&Bbuf[bi_][ks_][lane * 8]);      \
      bl_c[ks_] = *reinterpret_cast<const bf16x8*>(&Bbuf[bi_][4 + ks_][lane * 8]);  \
    }                                                                               \
    const int code_ = (ct_) * 16 + col;                                             \
    const float cn_ = CnS[code_];                                                   \
    __builtin_amdgcn_s_setprio(1);                                                  \
    f32x4 aA = (f32x4){0.f,0.f,0.f,0.f};                                            \
    f32x4 aB = (f32x4){0.f,0.f,0.f,0.f};                                            \
    f32x4 aC = (f32x4){0.f,0.f,0.f,0.f};                                            \
    _Pragma("unroll")                                                               \
    for (int ks_ = 0; ks_ < 4; ++ks_) {                                             \
      aA = __builtin_amdgcn_mfma_f32_16x16x32_bf16(ah[ks_], bh_c[ks_], aA, 0,0,0);  \
      aB = __builtin_amdgcn_mfma_f32_16x16x32_bf16(ah[ks_], bl_c[ks_], aB, 0,0,0);  \
      aC = __builtin_amdgcn_mfma_f32_16x16x32_bf16(al[ks_], bh_c[ks_], aC, 0,0,0);  \
    }                                                                               \
    _Pragma("unroll")                                                               \
    for (int reg_ = 0; reg_ < 4; ++reg_) {                                          \
      float S = fmaf(-2.0f, (aA[reg_] + aB[reg_]) + aC[reg_], cn_);                 \
      if (S < s1[reg_]) { s2[reg_] = s1[reg_]; s1[reg_] = S; i1[reg_] = code_; }    \
      else if (S < s2[reg_]) { s2[reg_] = S; }                                      \
    }                                                                               \
    __builtin_amdgcn_s_setprio(0); }

#define PHASE(t_, bi_)                                                              \
  { asm volatile("s_waitcnt vmcnt(4)" ::: "memory");                                \
    __builtin_amdgcn_s_barrier();                                                   \
    __builtin_amdgcn_sched_barrier(0);                                              \
    COMP(bi_, t_);                                                                  \
    STAGE(((t_) + 3) & 63, ((bi_) + 3) & 3); }

  __syncthreads();   // CnS visible
  STAGE(0, 0); STAGE(1, 1); STAGE(2, 2);
  for (int g = 0; g < NCT; g += 4) {
    PHASE(g + 0, 0);
    PHASE(g + 1, 1);
    PHASE(g + 2, 2);
    PHASE(g + 3, 3);
  }
#undef PHASE
#undef STAGE
#undef COMP

  // cross-lane (16-col group) min1/min2 merge
#pragma unroll
  for (int m = 1; m < 16; m <<= 1) {
#pragma unroll
    for (int reg = 0; reg < 4; ++reg) {
      float os1 = __shfl_xor(s1[reg], m, 64);
      float os2 = __shfl_xor(s2[reg], m, 64);
      int   oi  = __shfl_xor(i1[reg], m, 64);
      if (os1 < s1[reg]) {
        s2[reg] = fminf(s1[reg], os2);
        s1[reg] = os1; i1[reg] = oi;
      } else {
        s2[reg] = fminf(s2[reg], os1);
      }
    }
  }

  // idx -> per-wave LDS + fused hard-row flagging (wave-local)
  if (col == 0) {
#pragma unroll
    for (int reg = 0; reg < 4; ++reg) {
      int wr = (lane >> 4) * 4 + reg;     // 0..15 within wave
      idxW[wave][wr] = i1[reg];
      if (s2[reg] - s1[reg] < TAU) {
        int p = atomicAdd(cnt, 1);
        if (p < M_TOTAL - 1) list[p] = (int)(baseRow + wave * 16 + wr);
      }
    }
  }
  // same-wave LDS write->read: in-order per wave

  // fused epilogue, FLAT-COALESCED: wave's 16 rows = 512 float4; lane handles
  // flat idx lane+64*it -> lanes 0-31 cover row 2*it fully, lanes 32-63 row 2*it+1.
  {
    const float* zW  = z      + ((size_t)baseRow + wave * 16) * D;
    float*       oW  = out_zq + ((size_t)baseRow + wave * 16) * D;
#pragma unroll
    for (int it = 0; it < 8; ++it) {
      const int flat = lane + 64 * it;     // 0..511
      const int r    = flat >> 5;          // row within wave (uniform per 32-lane half)
      const int d4   = flat & 31;
      const int idx  = idxW[wave][r];
      float4 cv = reinterpret_cast<const float4*>(cb + (size_t)idx * D)[d4];
      float4 zv = reinterpret_cast<const float4*>(zW)[flat];
      float dx = cv.x - zv.x, dy = cv.y - zv.y, dz = cv.z - zv.z, dw = cv.w - zv.w;
      float4 st;
      st.x = zv.x + dx; st.y = zv.y + dy; st.z = zv.z + dz; st.w = zv.w + dw;
      reinterpret_cast<float4*>(oW)[flat] = st;
      float sq = fmaf(dx, dx, fmaf(dy, dy, fmaf(dz, dz, dw * dw)));
      sq += __shfl_xor(sq, 1, 64);  sq += __shfl_xor(sq, 2, 64);
      sq += __shfl_xor(sq, 4, 64);  sq += __shfl_xor(sq, 8, 64);
      sq += __shfl_xor(sq, 16, 64);                       // reduce within 32-lane half
      if ((lane & 31) == 0) {
        size_t m = (size_t)baseRow + wave * 16 + r;
        out_q[m]  = sq * 0.0078125f;   // /128
        out_iF[m] = (float)idx;
      }
    }
  }
}

// ---------------- kernel 2: FULL RESCAN via cbT — also rewrites z_q/loss/idx ----------
__global__ __launch_bounds__(256, 4) void vq_rescan_cbT(
    const float* __restrict__ z, const float* __restrict__ cb,
    const float4* __restrict__ cbT4, const float* __restrict__ Cn,
    const int* __restrict__ cnt, const int* __restrict__ list,
    float* __restrict__ out_zq, float* __restrict__ out_q,
    float* __restrict__ out_iF) {
  __shared__ __align__(16) float Zs[D];
  __shared__ float sRed[256];
  __shared__ int   iRed[256];
  const int t = threadIdx.x;
  int n = *cnt; if (n > M_TOTAL - 1) n = M_TOTAL - 1;

  for (int it = blockIdx.x; it < n; it += gridDim.x) {
    const int row = list[it];
    if (t < 32) {
      reinterpret_cast<float4*>(Zs)[t] =
          reinterpret_cast<const float4*>(z + (size_t)row * D)[t];
    }
    __syncthreads();

    float a0 = 0.f, a1 = 0.f, a2 = 0.f, a3 = 0.f;
#pragma unroll 8
    for (int d = 0; d < D; ++d) {
      float  zv = Zs[d];                 // LDS broadcast
      float4 cv = cbT4[(d << 8) + t];    // lane-contiguous, L2-hit
      a0 = fmaf(zv, cv.x, a0);
      a1 = fmaf(zv, cv.y, a1);
      a2 = fmaf(zv, cv.z, a2);
      a3 = fmaf(zv, cv.w, a3);
    }
    const float A = np_norm128(Zs);

    const int kb = t * 4;
    float bd = 3.402823466e+38f; int bi = 0;
    {  // ascending k, strict <: numpy first-occurrence
      float d0 = __fadd_rn(__fsub_rn(A, __fmul_rn(2.0f, a0)), Cn[kb + 0]);
      float d1 = __fadd_rn(__fsub_rn(A, __fmul_rn(2.0f, a1)), Cn[kb + 1]);
      float d2 = __fadd_rn(__fsub_rn(A, __fmul_rn(2.0f, a2)), Cn[kb + 2]);
      float d3 = __fadd_rn(__fsub_rn(A, __fmul_rn(2.0f, a3)), Cn[kb + 3]);
      if (d0 < bd) { bd = d0; bi = kb + 0; }
      if (d1 < bd) { bd = d1; bi = kb + 1; }
      if (d2 < bd) { bd = d2; bi = kb + 2; }
      if (d3 < bd) { bd = d3; bi = kb + 3; }
    }
    sRed[t] = bd; iRed[t] = bi;
    __syncthreads();
    for (int w = 128; w > 0; w >>= 1) {
      if (t < w) {
        float o = sRed[t + w]; int oi = iRed[t + w];
        if (o < sRed[t] || (o == sRed[t] && oi < iRed[t])) { sRed[t] = o; iRed[t] = oi; }
      }
      __syncthreads();
    }
    // rewrite this row's outputs with the exact winner
    const int win = iRed[0];
    if (t < 32) {
      float4 zv = reinterpret_cast<const float4*>(Zs)[t];
      float4 cv = reinterpret_cast<const float4*>(cb + (size_t)win * D)[t];
      float dx = cv.x - zv.x, dy = cv.y - zv.y, dz = cv.z - zv.z, dw = cv.w - zv.w;
      float4 st;
      st.x = zv.x + dx; st.y = zv.y + dy; st.z = zv.z + dz; st.w = zv.w + dw;
      reinterpret_cast<float4*>(out_zq + (size_t)row * D)[t] = st;
      float sq = fmaf(dx, dx, fmaf(dy, dy, fmaf(dz, dz, dw * dw)));
      sq += __shfl_xor(sq, 1, 64);  sq += __shfl_xor(sq, 2, 64);
      sq += __shfl_xor(sq, 4, 64);  sq += __shfl_xor(sq, 8, 64);
      sq += __shfl_xor(sq, 16, 64);
      if (t == 0) {
        out_q[row]  = sq * 0.0078125f;
        out_iF[row] = (float)win;
      }
    }
    __syncthreads();   // protect Zs before next iteration
  }
}

// ---------------- kernel 3: commit_loss = quant_loss (after rescan; frees out2 scratch)
__global__ void vq_copy(const float* __restrict__ q, float* __restrict__ c) {
  int m = blockIdx.x * 256 + threadIdx.x;
  c[m] = q[m];
}

// ---------------- FALLBACK main: R4 kernel verbatim (validated, ~320 us) ---------------
__global__ __launch_bounds__(256) void vq_main_fp32(
    const float* __restrict__ z, const float* __restrict__ cb,
    const float* __restrict__ Cn,
    float* __restrict__ out_zq, float* __restrict__ out_q,
    float* __restrict__ out_c, float* __restrict__ out_i) {
  __shared__ float Zt[64 * D];
  __shared__ float Ct[64 * D];
  __shared__ float Arow[64];
  __shared__ int   idxArr[64];

  const int t  = threadIdx.x;
  const int ty = t >> 4;
  const int tx = t & 15;
  const int baseRow = blockIdx.x * 64;

  for (int s = t; s < 64 * (D / 4); s += 256) {
    int r = s >> 5, d4 = s & 31;
    float4 v = reinterpret_cast<const float4*>(z)[(size_t)(baseRow + r) * (D / 4) + d4];
    int colx = d4 ^ (r & 7);
    *reinterpret_cast<float4*>(&Zt[r * D + colx * 4]) = v;
  }
  __syncthreads();

  if (t < 64) {
    const int rs = t & 7;
    float r8[8];
#pragma unroll
    for (int j = 0; j < 8; ++j) {
      float v = Zt[t * D + (((j >> 2) ^ rs) << 2) + (j & 3)];
      r8[j] = __fmul_rn(v, v);
    }
    for (int i = 8; i < D; i += 8) {
#pragma unroll
      for (int j = 0; j < 8; ++j) {
        int d = i + j;
        float v = Zt[t * D + (((d >> 2) ^ rs) << 2) + (d & 3)];
        r8[j] = __fadd_rn(r8[j], __fmul_rn(v, v));
      }
    }
    Arow[t] = __fadd_rn(__fadd_rn(__fadd_rn(r8[0], r8[1]), __fadd_rn(r8[2], r8[3])),
                        __fadd_rn(__fadd_rn(r8[4], r8[5]), __fadd_rn(r8[6], r8[7])));
  }

  float s1[4]; int i1[4];
#pragma unroll
  for (int i = 0; i < 4; ++i) { s1[i] = 3.402823466e+38f; i1[i] = 0; }

  const int zsw = ty & 7;
  const int csw = tx & 7;

  for (int kt = 0; kt < 16; ++kt) {
    __syncthreads();
    for (int s = t; s < 64 * (D / 4); s += 256) {
      int r = s >> 5, d4 = s & 31;
      float4 v = reinterpret_cast<const float4*>(cb)[(size_t)(kt * 64 + r) * (D / 4) + d4];
      int colx = d4 ^ (r & 7);
      *reinterpret_cast<float4*>(&Ct[r * D + colx * 4]) = v;
    }
    __syncthreads();

    float acc[4][4];
#pragma unroll
    for (int i = 0; i < 4; ++i)
#pragma unroll
      for (int j = 0; j < 4; ++j) acc[i][j] = 0.f;

    for (int d4 = 0; d4 < 32; ++d4) {
      float4 za[4], cv[4];
      int zc = (d4 ^ zsw) * 4;
      int cc = (d4 ^ csw) * 4;
#pragma unroll
      for (int i = 0; i < 4; ++i)
        za[i] = *reinterpret_cast<const float4*>(&Zt[(ty + 16 * i) * D + zc]);
#pragma unroll
      for (int j = 0; j < 4; ++j)
        cv[j] = *reinterpret_cast<const float4*>(&Ct[(tx + 16 * j) * D + cc]);
#pragma unroll
      for (int i = 0; i < 4; ++i)
#pragma unroll
        for (int j = 0; j < 4; ++j) {
          acc[i][j] = fmaf(za[i].x, cv[j].x, acc[i][j]);
          acc[i][j] = fmaf(za[i].y, cv[j].y, acc[i][j]);
          acc[i][j] = fmaf(za[i].z, cv[j].z, acc[i][j]);
          acc[i][j] = fmaf(za[i].w, cv[j].w, acc[i][j]);
        }
    }

    float ch[4]; int kg[4];
#pragma unroll
    for (int j = 0; j < 4; ++j) {
      kg[j] = kt * 64 + tx + 16 * j;
      ch[j] = Cn[kg[j]];
    }
#pragma unroll
    for (int i = 0; i < 4; ++i) {
      float a = Arow[ty + 16 * i];
#pragma unroll
      for (int j = 0; j < 4; ++j) {
        float dist = __fadd_rn(__fsub_rn(a, __fmul_rn(2.0f, acc[i][j])), ch[j]);
        if (dist < s1[i]) { s1[i] = dist; i1[i] = kg[j]; }
      }
    }
  }

#pragma unroll
  for (int m = 1; m < 16; m <<= 1) {
#pragma unroll
    for (int i = 0; i < 4; ++i) {
      float os = __shfl_xor(s1[i], m, 64);
      int   oi = __shfl_xor(i1[i], m, 64);
      if (os < s1[i] || (os == s1[i] && oi < i1[i])) { s1[i] = os; i1[i] = oi; }
    }
  }

  if (tx == 0) {
#pragma unroll
    for (int i = 0; i < 4; ++i) idxArr[ty + 16 * i] = i1[i];
  }
  __syncthreads();

  {
    int r = t >> 2, q = t & 3;
    int idx = idxArr[r];
    size_t m = (size_t)baseRow + r;
    const float4* cq = reinterpret_cast<const float4*>(cb + (size_t)idx * D);
    const float4* zr = reinterpret_cast<const float4*>(z + m * D);
    float4*       o4 = reinterpret_cast<float4*>(out_zq + m * D);
    float sum = 0.f;
#pragma unroll
    for (int e = 0; e < 8; ++e) {
      int d4 = q * 8 + e;
      float4 cv = cq[d4];
      float4 zv = zr[d4];
      float dx = cv.x - zv.x, dy = cv.y - zv.y, dz = cv.z - zv.z, dw = cv.w - zv.w;
      float4 st;
      st.x = zv.x + dx; st.y = zv.y + dy; st.z = zv.z + dz; st.w = zv.w + dw;
      o4[d4] = st;
      sum = fmaf(dx, dx, sum); sum = fmaf(dy, dy, sum);
      sum = fmaf(dz, dz, sum); sum = fmaf(dw, dw, sum);
    }
    sum += __shfl_xor(sum, 1, 64);
    sum += __shfl_xor(sum, 2, 64);
    if (q == 0) {
      float lv = sum * 0.0078125f;
      out_q[m] = lv;
      out_c[m] = lv;
      out_i[m] = (float)idx;
    }
  }
}

extern "C" void kernel_launch(void* const* d_in, const int* in_sizes, int n_in,
                              void* d_out, int out_size, void* d_ws, size_t ws_size,
                              hipStream_t stream) {
  const float* z  = (const float*)d_in[0];   // [16,4096,128] fp32
  const float* cb = (const float*)d_in[1];   // [1024,128] fp32

  float* out0 = (float*)d_out;               // z_q_ste  [M,128]
  float* out1 = out0 + (size_t)M_TOTAL * D;  // quant_loss [M]
  float* out2 = out1 + M_TOTAL;              // commit_loss [M]
  float* out3 = out2 + M_TOTAL;              // indices (as float) [M]

  float* Cn = (float*)((char*)d_ws + WS_CN);
  // cnt/list live in out2 during score+rescan; vq_copy then writes commit_loss there.
  int* cnt  = (int*)out2;
  int* list = (int*)out2 + 1;

  if (ws_size >= WS_REQ2) {
    short*  Bh   = (short*)((char*)d_ws + WS_BH);
    short*  Bl   = (short*)((char*)d_ws + WS_BL);
    float4* cbT4 = (float4*)((char*)d_ws + WS_CBT);
    vq_prep_all<<<196, 256, 0, stream>>>(cb, Cn, cnt, Bh, Bl, cbT4);
    vq_score<<<M_TOTAL / BM, 256, 0, stream>>>(z, cb, Cn, Bh, Bl,
                                               out0, out1, out3, cnt, list);
    vq_rescan_cbT<<<1024, 256, 0, stream>>>(z, cb, cbT4, Cn, cnt, list,
                                            out0, out1, out3);
    vq_copy<<<M_TOTAL / 256, 256, 0, stream>>>(out1, out2);
  } else {
    vq_prep_all<<<4, 256, 0, stream>>>(cb, Cn, cnt, nullptr, nullptr, nullptr);
    vq_main_fp32<<<M_TOTAL / 64, 256, 0, stream>>>(z, cb, Cn, out0, out1, out2, out3);
  }
}